// Round 5
// baseline (288.315 us; speedup 1.0000x reference)
//
#include <hip/hip_runtime.h>

typedef unsigned short u16;
typedef unsigned int   u32;

typedef __bf16 bf16x8_t __attribute__((ext_vector_type(8)));
typedef bf16x8_t bf16x8 __attribute__((may_alias));
typedef float f32x4_t __attribute__((ext_vector_type(4)));
typedef f32x4_t f32x4 __attribute__((may_alias));
typedef u32 u32x4_t __attribute__((ext_vector_type(4)));
typedef u32x4_t u32x4 __attribute__((may_alias));
typedef u32 u32x2_t __attribute__((ext_vector_type(2)));
typedef u32x2_t u32x2 __attribute__((may_alias));

__device__ __forceinline__ u16 f2b(float f) {        // RNE via hw cvt
  __bf16 h = (__bf16)f; u16 u; __builtin_memcpy(&u, &h, 2); return u;
}
__device__ __forceinline__ float b2f(u16 u) {
  u32 i = ((u32)u) << 16; float f; __builtin_memcpy(&f, &i, 4); return f;
}
__device__ __forceinline__ bf16x8_t cvt8(const float* p) {
  f32x4_t a = *(const f32x4*)p;
  f32x4_t b = *(const f32x4*)(p + 4);
  bf16x8_t v;
  v[0]=(__bf16)a[0]; v[1]=(__bf16)a[1]; v[2]=(__bf16)a[2]; v[3]=(__bf16)a[3];
  v[4]=(__bf16)b[0]; v[5]=(__bf16)b[1]; v[6]=(__bf16)b[2]; v[7]=(__bf16)b[3];
  return v;
}
// async global->LDS, 16B/lane (proper addrspacecast)
typedef __attribute__((address_space(1))) const void* as1cv;
typedef __attribute__((address_space(3))) void* as3v;
__device__ __forceinline__ void gld16(const u16* g, u16* l) {
  __builtin_amdgcn_global_load_lds((as1cv)g, (as3v)l, 16, 0, 0);
}

#define EPS 1.1920929e-07f

// ---------------------------------------------------------------------------
// cvt_pack: x (nx f32) + Wq|Wk|Wv|Wo (1M f32 each) -> bf16 blob (r10)
// ---------------------------------------------------------------------------
#define WSZ (1024 * 1024)
__global__ __launch_bounds__(256) void cvt_pack(
    const float* __restrict__ x, const float* __restrict__ wq,
    const float* __restrict__ wk, const float* __restrict__ wv,
    const float* __restrict__ wo, u16* __restrict__ dst, int nx)
{
  int idx4 = blockIdx.x * 256 + threadIdx.x;
  const int total4 = (nx + 4 * WSZ) >> 2;
  for (; idx4 < total4; idx4 += gridDim.x * 256) {
    int i = idx4 << 2;
    const float* src;
    if (i < nx) src = x + i;
    else {
      int o = i - nx;
      if      (o <     WSZ) src = wq + o;
      else if (o < 2 * WSZ) src = wk + o - WSZ;
      else if (o < 3 * WSZ) src = wv + o - 2 * WSZ;
      else                  src = wo + o - 3 * WSZ;
    }
    f32x4_t v = *(const f32x4*)src;
    u32x2_t p;
    p[0] = (u32)f2b(v[0]) | ((u32)f2b(v[1]) << 16);
    p[1] = (u32)f2b(v[2]) | ((u32)f2b(v[3]) << 16);
    *(u32x2*)(dst + i) = p;
  }
}

// ---------------------------------------------------------------------------
// gemm8 (r12, NEW): 256x256 tile, BK=64, 512 threads (8 waves, 2Mx4N),
// deep-pipelined 4-phase/K-tile schedule derived from the 8-phase template.
//
// LDS 128KB: per dbuf d in {0,1}: A halves (d*2+h)*16KB, B at +64KB same.
// Half = 128 rows x 64 bf16 (128B/row, 8 x 16B chunks).
//
// Swizzle (bank-conflict-free frag reads): LDS content
//   LDS[r][c] = Gtile[r][c ^ (r&7)]   (16B-chunk granularity, involution)
// achieved via linear gld16 dest + inverse-swizzled per-lane GLOBAL source
// (rule #21: both-sides-or-neither). Frag read at row, chunk (ks*4+quad):
//   addr = row*128 + ((ks*4+quad) ^ (row&7))*16 ; row&7 == col&7 across the
// 16 lanes of a quarter -> 8 distinct chunks -> all 32 banks, 2-way (free).
//
// Schedule (race-free ledger):
//  block k (4 phases) reads dbuf k&1 (kt k); each phase stages ONE half-tile
//  of kt k+1 into dbuf (k+1)&1 -- that dbuf's reads ended at block k-1's
//  closing __syncthreads, so no write-before-read hazard. Block boundary =
//  __syncthreads() (implicit vmcnt(0) drains exactly the 8 in-flight loads;
//  ~4 phases of latency cover, panels are L2-resident per r4 FETCH).
//  Phase: {ds_read frags || 2 gld16 -> s_barrier -> setprio(1) 16 MFMA
//  setprio(0) -> s_barrier}. T5 per m218b/m224 (+21-39% on phase-split).
// ---------------------------------------------------------------------------
template<int NORM, int CF32>
__global__ __launch_bounds__(512, 2) void gemm8(
    const u16* __restrict__ A, const u16* __restrict__ Bm,
    const float* __restrict__ bias0, const float* __restrict__ bias1, const float* __restrict__ bias2,
    const float* __restrict__ qn, const float* __restrict__ kn,
    void* __restrict__ C, int M, int K, int ldc)
{
  __shared__ alignas(16) u16 lds[65536];     // 128 KB
  const int t = threadIdx.x;
  const int lane = t & 63, wave = t >> 6;
  const int quad = lane >> 4, col = lane & 15;
  const int wm = wave >> 2, wn = wave & 3;   // 2 M-halves x 4 N-quarters

  // bijective XCD swizzle on flat block id (T1); disabled if nwg%8 != 0
  const int nwg = gridDim.x * gridDim.y;
  int fid = blockIdx.y * gridDim.x + blockIdx.x;
  int wg = (nwg & 7) ? fid : ((fid & 7) * (nwg >> 3) + (fid >> 3));
  const int m0 = (wg % gridDim.x) * 256;
  const int n0 = (wg / gridDim.x) * 256;

  // staging geometry: thread t stages row srow=t>>3 (of a 64-row slice q),
  // 16B chunk (t&7); global source chunk pre-swizzled by ^(srow&7).
  const int srow = t >> 3;
  const int sx = ((t & 7) ^ (srow & 7)) << 3;          // u16 offset in 64-elem row
  const u16* asrc[2][2];
  const u16* bsrc[2][2];
#pragma unroll
  for (int h = 0; h < 2; ++h)
#pragma unroll
    for (int q = 0; q < 2; ++q) {
      int ar = m0 + h * 128 + q * 64 + srow; if (ar >= M) ar = M - 1;
      asrc[h][q] = A  + (size_t)ar * K + sx;
      int br = n0 + h * 128 + q * 64 + srow;           // N is exact multiple of 256
      bsrc[h][q] = Bm + (size_t)br * K + sx;
    }
  const int dst8 = t * 8;                              // u16 units, 16B/thread

  // prologue: stage kt0 into dbuf0, full drain
#pragma unroll
  for (int h = 0; h < 2; ++h)
#pragma unroll
    for (int q = 0; q < 2; ++q) {
      gld16(asrc[h][q],         lds +         h * 8192 + q * 4096 + dst8);
      gld16(bsrc[h][q], lds + 32768 + h * 8192 + q * 4096 + dst8);
    }
  __syncthreads();

  f32x4_t acc[8][4] = {};
  const int nt = K >> 6;
  for (int k = 0; k < nt; ++k) {
    const int d = k & 1, nk = k + 1, nd = nk & 1;
    const int koff = nk << 6;
    const u16* Ab = lds +         (2 * d + wm) * 8192;
    const u16* Bb = lds + 32768 + (2 * d + (wn >> 1)) * 8192;
    const int browb = ((wn & 1) * 64) << 6;            // B row base (u16 units)
    bf16x8 bfr[4];
#pragma unroll
    for (int p = 0; p < 4; ++p) {
      const int g = p & 1, ks = p >> 1;
      const int ck = (((ks * 4 + quad) ^ (col & 7)) << 3);
      if (g == 0) {
#pragma unroll
        for (int nj = 0; nj < 4; ++nj)
          bfr[nj] = *(const bf16x8*)(Bb + browb + ((nj * 16 + col) << 6) + ck);
      }
      bf16x8 af[4];
#pragma unroll
      for (int i = 0; i < 4; ++i)
        af[i] = *(const bf16x8*)(Ab + (((g * 4 + i) * 16 + col) << 6) + ck);
      if (nk < nt) {                                   // stage half-tile p of kt k+1
        if (p == 0) {
          gld16(asrc[0][0] + koff, lds + (2 * nd) * 8192 + dst8);
          gld16(asrc[0][1] + koff, lds + (2 * nd) * 8192 + 4096 + dst8);
        } else if (p == 1) {
          gld16(asrc[1][0] + koff, lds + (2 * nd + 1) * 8192 + dst8);
          gld16(asrc[1][1] + koff, lds + (2 * nd + 1) * 8192 + 4096 + dst8);
        } else if (p == 2) {
          gld16(bsrc[0][0] + koff, lds + 32768 + (2 * nd) * 8192 + dst8);
          gld16(bsrc[0][1] + koff, lds + 32768 + (2 * nd) * 8192 + 4096 + dst8);
        } else {
          gld16(bsrc[1][0] + koff, lds + 32768 + (2 * nd + 1) * 8192 + dst8);
          gld16(bsrc[1][1] + koff, lds + 32768 + (2 * nd + 1) * 8192 + 4096 + dst8);
        }
      }
      __builtin_amdgcn_s_barrier();
      __builtin_amdgcn_s_setprio(1);
#pragma unroll
      for (int i = 0; i < 4; ++i)
#pragma unroll
        for (int nj = 0; nj < 4; ++nj)
          acc[g * 4 + i][nj] = __builtin_amdgcn_mfma_f32_16x16x32_bf16(
              af[i], bfr[nj], acc[g * 4 + i][nj], 0, 0, 0);
      __builtin_amdgcn_s_setprio(0);
      if (p < 3) __builtin_amdgcn_s_barrier();
    }
    __syncthreads();   // block boundary: drains the 8 staged loads + sync
  }

  // epilogue: bias + (optional) fused RMSNorm over the wave's 64-col head
  const int gnb = n0 + wn * 64;                        // 64-aligned head base
  const int seg = gnb >> 10, nl = gnb & 1023;
  const float* bias = seg == 0 ? bias0 : (seg == 1 ? bias1 : bias2);
  float bz[4], wz[4];
#pragma unroll
  for (int nj = 0; nj < 4; ++nj) {
    bz[nj] = bias[nl + nj * 16 + col];
    if (NORM) wz[nj] = (seg == 0 ? qn : kn)[nj * 16 + col];
  }
  const bool donorm = NORM && seg < 2;
#pragma unroll
  for (int mi = 0; mi < 8; ++mi) {
#pragma unroll
    for (int rr = 0; rr < 4; ++rr) {
      int gm = m0 + wm * 128 + mi * 16 + quad * 4 + rr;
      float v[4];
#pragma unroll
      for (int nj = 0; nj < 4; ++nj) v[nj] = acc[mi][nj][rr] + bz[nj];
      if (donorm) {
        float ss = v[0]*v[0] + v[1]*v[1] + v[2]*v[2] + v[3]*v[3];
        ss += __shfl_xor(ss, 1);
        ss += __shfl_xor(ss, 2);
        ss += __shfl_xor(ss, 4);
        ss += __shfl_xor(ss, 8);
        float sc = rsqrtf(ss * (1.0f / 64.0f) + EPS);
#pragma unroll
        for (int nj = 0; nj < 4; ++nj) v[nj] *= sc * wz[nj];
      }
      if (gm < M) {
#pragma unroll
        for (int nj = 0; nj < 4; ++nj) {
          int gn = gnb + nj * 16 + col;
          if (CF32) ((float*)C)[(size_t)gm * ldc + gn] = v[nj];
          else      ((u16*)C)[(size_t)gm * ldc + gn] = f2b(v[nj]);
        }
      }
    }
  }
}

// ---------------------------------------------------------------------------
// FALLBACK tier kernels (r9, unchanged)
// ---------------------------------------------------------------------------
#define BK 32
template<int AF32, int CF32>
__global__ __launch_bounds__(256, 2) void gemm_bt(
    const void* __restrict__ Av,
    const float* __restrict__ B0, const float* __restrict__ B1, const float* __restrict__ B2,
    const float* __restrict__ bias0, const float* __restrict__ bias1, const float* __restrict__ bias2,
    void* __restrict__ C, int M, int K, int ldc)
{
  __shared__ alignas(16) u16 As[128 * BK];
  __shared__ alignas(16) u16 Bs[128 * BK];
  const int t = threadIdx.x;
  const int lane = t & 63, wave = t >> 6;
  const int quad = lane >> 4, col = lane & 15;
  const int m0 = blockIdx.x * 128, n0 = blockIdx.y * 128;
  const int seg = n0 >> 10;
  const float* B    = seg == 0 ? B0    : (seg == 1 ? B1    : B2);
  const float* bias = seg == 0 ? bias0 : (seg == 1 ? bias1 : bias2);
  const int nl0 = n0 & 1023;
  const int wm = (wave >> 1) * 64, wn = (wave & 1) * 64;
  const int lrow = t >> 2;
  const int lcol = (t & 3) * 8;
  int ar0 = m0 + lrow;      if (ar0 >= M) ar0 = M - 1;
  int ar1 = m0 + 64 + lrow; if (ar1 >= M) ar1 = M - 1;
  const float* bp0 = B + (size_t)(nl0 + lrow) * K + lcol;
  const float* bp1 = B + (size_t)(nl0 + 64 + lrow) * K + lcol;
  const float* apf0 = (const float*)Av + (size_t)ar0 * K + lcol;
  const float* apf1 = (const float*)Av + (size_t)ar1 * K + lcol;
  const u16*   aph0 = (const u16*)Av   + (size_t)ar0 * K + lcol;
  const u16*   aph1 = (const u16*)Av   + (size_t)ar1 * K + lcol;
  u16* lA0 = As + t * 8;
  u16* lA1 = As + 64 * BK + t * 8;
  u16* lB0 = Bs + t * 8;
  u16* lB1 = Bs + 64 * BK + t * 8;

  f32x4_t acc[4][4] = {};
  for (int k0 = 0; k0 < K; k0 += BK) {
    bf16x8_t va0, va1, vb0, vb1;
    if (AF32) { va0 = cvt8(apf0 + k0); va1 = cvt8(apf1 + k0); }
    else {
      u32x4_t r0 = *(const u32x4*)(aph0 + k0);
      u32x4_t r1 = *(const u32x4*)(aph1 + k0);
      __builtin_memcpy(&va0, &r0, 16);
      __builtin_memcpy(&va1, &r1, 16);
    }
    vb0 = cvt8(bp0 + k0);
    vb1 = cvt8(bp1 + k0);
    __syncthreads();
    *(bf16x8*)lA0 = va0; *(bf16x8*)lA1 = va1;
    *(bf16x8*)lB0 = vb0; *(bf16x8*)lB1 = vb1;
    __syncthreads();
    bf16x8 af[4], bfr[4];
#pragma unroll
    for (int i = 0; i < 4; ++i) {
      af[i]  = *(const bf16x8*)(As + (wm + i * 16 + col) * BK + quad * 8);
      bfr[i] = *(const bf16x8*)(Bs + (wn + i * 16 + col) * BK + quad * 8);
    }
#pragma unroll
    for (int i = 0; i < 4; ++i)
#pragma unroll
      for (int j = 0; j < 4; ++j)
        acc[i][j] = __builtin_amdgcn_mfma_f32_16x16x32_bf16(af[i], bfr[j], acc[i][j], 0, 0, 0);
  }
#pragma unroll
  for (int j = 0; j < 4; ++j) {
    int gn = n0 + wn + j * 16 + col;
    float bz = bias[nl0 + wn + j * 16 + col];
#pragma unroll
    for (int i = 0; i < 4; ++i) {
#pragma unroll
      for (int rr = 0; rr < 4; ++rr) {
        int gm = m0 + wm + i * 16 + quad * 4 + rr;
        if (gm < M) {
          float v = acc[i][j][rr] + bz;
          if (CF32) ((float*)C)[(size_t)gm * ldc + gn] = v;
          else      ((u16*)C)[(size_t)gm * ldc + gn] = f2b(v);
        }
      }
    }
  }
}

__global__ __launch_bounds__(256) void rmsnorm_qk(
    u16* __restrict__ qkv, const float* __restrict__ qn, const float* __restrict__ kn, int T)
{
  int gid = blockIdx.x * 256 + threadIdx.x;
  int row = gid >> 4, sub = gid & 15;
  if (row >= 2 * T * 16) return;
  int which = row >= T * 16;
  int r = which ? row - T * 16 : row;
  int tok = r >> 4, head = r & 15;
  u16* p = qkv + (size_t)tok * 3072 + which * 1024 + head * 64 + sub * 4;
  u16 d0 = p[0], d1 = p[1], d2 = p[2], d3 = p[3];
  float f0 = b2f(d0), f1 = b2f(d1), f2v = b2f(d2), f3 = b2f(d3);
  float ss = f0 * f0 + f1 * f1 + f2v * f2v + f3 * f3;
  ss += __shfl_xor(ss, 1);
  ss += __shfl_xor(ss, 2);
  ss += __shfl_xor(ss, 4);
  ss += __shfl_xor(ss, 8);
  float sc = rsqrtf(ss * (1.0f / 64.0f) + EPS);
  const float* w = which ? kn : qn;
  p[0] = f2b(f0 * sc * w[sub * 4 + 0]);
  p[1] = f2b(f1 * sc * w[sub * 4 + 1]);
  p[2] = f2b(f2v * sc * w[sub * 4 + 2]);
  p[3] = f2b(f3 * sc * w[sub * 4 + 3]);
}

// ---------------------------------------------------------------------------
// Flash attention v6 (r4-verified win: 110 -> <74 us): HEAD-MAJOR grid,
// id%8 == head%8 -> XCD balance + K/V L2 reuse across qt. Unchanged this round.
// ---------------------------------------------------------------------------
#define SKS 68
#define SVS 68
#define SPS 68
__global__ __launch_bounds__(256, 4) void attn_fwd(
    const u16* __restrict__ qkv, const int* __restrict__ cu, u16* __restrict__ out)
{
  __shared__ alignas(16) u16 Ks[64 * SKS];
  __shared__ alignas(16) u16 Vts[64 * SVS];
  __shared__ alignas(16) u16 Ps[8 * 16 * SPS];   // 4 waves x 2 row-sets
  const int seq = blockIdx.z, head = blockIdx.x, qt = blockIdx.y;
  const int start = cu[seq], len = cu[seq + 1] - start;
  const int q0 = qt * 128;
  if (q0 >= len) return;
  const int t = threadIdx.x;
  const int lane = t & 63, wave = t >> 6, quad = lane >> 4, col = lane & 15;

  const int rA = q0 + wave * 16 + col, rB = rA + 64;
  const u16* qpA = qkv + (size_t)(start + (rA < len ? rA : len - 1)) * 3072 + head * 64 + quad * 8;
  const u16* qpB = qkv + (size_t)(start + (rB < len ? rB : len - 1)) * 3072 + head * 64 + quad * 8;
  bf16x8 qfA0 = *(const bf16x8*)qpA;
  bf16x8 qfA1 = *(const bf16x8*)(qpA + 32);
  bf16x8 qfB0 = *(const bf16x8*)qpB;
  bf16x8 qfB1 = *(const bf16x8*)(qpB + 32);

  f32x4_t accOA[4] = {}, accOB[4] = {};
  float lA[4] = {}, lB[4] = {};                  // per-lane partial row sums
  const float SC = 0.125f * 1.44269504089f;

  // staging (r11): sp=t>>3 -> (kc,kh); dc=t&7; key pair (keyA, keyA+16)
  const int sp = t >> 3, dc = t & 7;
  const int kc = sp & 15, kh = sp >> 4;
  const int keyA = kc + 32 * kh;
  u16* ksA = Ks + keyA * SKS + dc * 8;
  u16* ksB = Ks + (keyA + 16) * SKS + dc * 8;
  const int vcol = kc * 4 + 2 * kh;
  const size_t kvbase = 1024 + head * 64 + dc * 8;

  const int nkv = (len + 63) >> 6;
  u32x4_t rkA, rkB, rvA, rvB;
  {   // prologue: tile 0
    int ta = start + (keyA      < len ? keyA      : len - 1);
    int tb = start + (keyA + 16 < len ? keyA + 16 : len - 1);
    const u16* pa = qkv + (size_t)ta * 3072 + kvbase;
    const u16* pb2 = qkv + (size_t)tb * 3072 + kvbase;
    rkA = *(const u32x4*)pa;   rvA = *(const u32x4*)(pa + 1024);
    rkB = *(const u32x4*)pb2;  rvB = *(const u32x4*)(pb2 + 1024);
  }

  for (int it = 0; it < nkv; ++it) {
    const int k0 = it << 6;
    __syncthreads();
    *(u32x4*)ksA = rkA;
    *(u32x4*)ksB = rkB;
    {
      const u16* a = (const u16*)&rvA;
      const u16* b = (const u16*)&rvB;
#pragma unroll
      for (int j = 0; j < 8; ++j) {
        u32 pk = (u32)a[j] | ((u32)b[j] << 16);
        *(u32*)(Vts + (dc * 8 + j) * SVS + vcol) = pk;
      }
    }
    __syncthreads();
    if (it + 1 < nkv) {                          // prefetch next tile
      int kb0 = k0 + 64;
      int ta = start + (kb0 + keyA      < len ? kb0 + keyA      : len - 1);
      int tb = start + (kb0 + keyA + 16 < len ? kb0 + keyA + 16 : len - 1);
      const u16* pa = qkv + (size_t)ta * 3072 + kvbase;
      const u16* pb2 = qkv + (size_t)tb * 3072 + kvbase;
      rkA = *(const u32x4*)pa;   rvA = *(const u32x4*)(pa + 1024);
      rkB = *(const u32x4*)pb2;  rvB = *(const u32x4*)(pb2 + 1024);
    }

    // S = Q.K^T for both row sets (independent chains)
    f32x4_t sgA[4], sgB[4];
#pragma unroll
    for (int g = 0; g < 4; ++g) {
      bf16x8 kb0 = *(const bf16x8*)(Ks + (g*16 + col) * SKS + quad * 8);
      bf16x8 kb1 = *(const bf16x8*)(Ks + (g*16 + col) * SKS + 32 + quad * 8);
      f32x4_t sA = {}, sB = {};
      sA = __builtin_amdgcn_mfma_f32_16x16x32_bf16(qfA0, kb0, sA, 0, 0, 0);
      sB = __builtin_amdgcn_mfma_f32_16x16x32_bf16(qfB0, kb0, sB, 0, 0, 0);
      sA = __builtin_amdgcn_mfma_f32_16x16x32_bf16(qfA1, kb1, sA, 0, 0, 0);
      sB = __builtin_amdgcn_mfma_f32_16x16x32_bf16(qfB1, kb1, sB, 0, 0, 0);
      sgA[g] = sA; sgB[g] = sB;
    }

    // P = exp2(S*SC), masked; key g*16+col -> column col*4+g (b64 rows)
    // L partials accumulate in-register from the SAME rounded bf16 values.
    const bool full = (k0 + 64 <= len);
    bool vg[4];
#pragma unroll
    for (int g = 0; g < 4; ++g) vg[g] = full || (k0 + g*16 + col) < len;
    u16* pwA = Ps + wave * (16 * SPS);
    u16* pwB = Ps + (4 + wave) * (16 * SPS);
#pragma unroll
    for (int r = 0; r < 4; ++r) {
      u16 peA[4], peB[4];
#pragma unroll
      for (int g = 0; g < 4; ++g) {
        float pA = exp2f(sgA[g][r] * SC);
        float pB = exp2f(sgB[g][r] * SC);
        peA[g] = vg[g] ? f2b(pA) : (u16)0;
        peB[g] = vg[g] ? f2b(pB) : (u16)0;
      }
      lA[r] += (b2f(peA[0]) + b2f(peA[1])) + (b2f(peA[2]) + b2f(peA[3]));
      lB[r] += (b2f(peB[0]) + b2f(peB[1])) + (b2f(peB[2]) + b2f(peB[3]));
      u32x2_t wA, wB;
      wA[0] = (u32)peA[0] | ((u32)peA[1] << 16);
      wA[1] = (u32)peA[2] | ((u32)peA[3] << 16);
      wB[0] = (u32)peB[0] | ((u32)peB[1] << 16);
      wB[1] = (u32)peB[2] | ((u32)peB[3] << 16);
      *(u32x2*)(pwA + (quad*4 + r) * SPS + col * 4) = wA;
      *(u32x2*)(pwB + (quad*4 + r) * SPS + col * 4) = wB;
    }
    __threadfence_block();

    bf16x8 pfA0 = *(const bf16x8*)(pwA + col * SPS + quad * 8);
    bf16x8 pfA1 = *(const bf16x8*)(pwA + col * SPS + 32 + quad * 8);
    bf16x8 pfB0 = *(const bf16x8*)(pwB + col * SPS + quad * 8);
    bf16x8 pfB1 = *(const bf16x8*)(pwB + col * SPS + 32 + quad * 8);
#pragma unroll
    for (int c = 0; c < 4; ++c) {
      bf16x8 vf0 = *(const bf16x8*)(Vts + (c*16 + col) * SVS + quad * 8);
      bf16x8 vf1 = *(const bf16x8*)(Vts + (c*16 + col) * SVS + 32 + quad * 8);
      accOA[c] = __builtin_amdgcn_mfma_f32_16x16x32_bf16(pfA0, vf0, accOA[c], 0, 0, 0);
      accOB[c] = __builtin_amdgcn_mfma_f32_16x16x32_bf16(pfB0, vf0, accOB[c], 0, 0, 0);
      accOA[c] = __builtin_amdgcn_mfma_f32_16x16x32_bf16(pfA1, vf1, accOA[c], 0, 0, 0);
      accOB[c] = __builtin_amdgcn_mfma_f32_16x16x32_bf16(pfB1, vf1, accOB[c], 0, 0, 0);
    }
  }

  // epilogue: finish L reduction across the 16 lanes sharing a quad
#pragma unroll
  for (int r = 0; r < 4; ++r) {
    float sA = lA[r], sB = lB[r];
    sA += __shfl_xor(sA, 1); sB += __shfl_xor(sB, 1);
    sA += __shfl_xor(sA, 2); sB += __shfl_xor(sB, 2);
    sA += __shfl_xor(sA, 4); sB += __shfl_xor(sB, 4);
    sA += __shfl_xor(sA, 8); sB += __shfl_xor(sB, 8);
    int rowA = q0 + wave * 16 + quad * 4 + r;
    int rowB = rowA + 64;
    if (rowA < len) {
      float inv = 1.0f / sA;
      u16* op = out + (size_t)(start + rowA) * 1024 + head * 64 + col;
      op[0]  = f2b(accOA[0][r] * inv);
      op[16] = f2b(accOA[1][r] * inv);
      op[32] = f2b(accOA[2][r] * inv);
      op[48] = f2b(accOA[3][r] * inv);
    }
    if (rowB < len) {
      float inv = 1.0f / sB;
      u16* op = out + (size_t)(start + rowB) * 1024 + head * 64 + col;
      op[0]  = f2b(accOB[0][r] * inv);
      op[16] = f2b(accOB[1][r] * inv);
      op[32] = f2b(accOB[2][r] * inv);
      op[48] = f2b(accOB[3][r] * inv);
    }
  }
}

__global__ void ws_too_small_sentinel(float* out) {
  if (threadIdx.x == 0 && blockIdx.x == 0) out[0] = 1024.0f;
}

// ---------------------------------------------------------------------------
extern "C" void kernel_launch(void* const* d_in, const int* in_sizes, int n_in,
                              void* d_out, int out_size, void* d_ws, size_t ws_size,
                              hipStream_t stream) {
  const float* x  = (const float*)d_in[0];
  const int*   cu = (const int*)d_in[1];
  const float* Wq = (const float*)d_in[2];
  const float* bq = (const float*)d_in[3];
  const float* Wk = (const float*)d_in[4];
  const float* bk = (const float*)d_in[5];
  const float* Wv = (const float*)d_in[6];
  const float* bv = (const float*)d_in[7];
  const float* qn = (const float*)d_in[8];
  const float* kn = (const float*)d_in[9];
  const float* Wo = (const float*)d_in[10];
  const float* bo = (const float*)d_in[11];

  const int T = in_sizes[0] / 1024;
  const int nseq = in_sizes[1] - 1;

  const size_t need_fast = ((size_t)T * 5120 + 4 * WSZ) * 2;   // 92.3 MB @ T=8192
  const size_t need_fall = (size_t)T * 4096 * 2;               // 67.1 MB

  u16* qkv  = (u16*)d_ws;
  u16* attn = qkv + (size_t)T * 3072;
  dim3 blk(256);

  if (ws_size >= need_fast) {
    u16* xb   = attn + (size_t)T * 1024;
    u16* wqkv = xb + (size_t)T * 1024;
    u16* wo   = wqkv + 3 * WSZ;
    cvt_pack<<<dim3(1024), blk, 0, stream>>>(x, Wq, Wk, Wv, Wo, xb, T * 1024);
    gemm8<1, 0><<<dim3((T + 255) / 256, 12), dim3(512), 0, stream>>>(
        xb, wqkv, bq, bk, bv, qn, kn, qkv, T, 1024, 3072);
    attn_fwd<<<dim3(16, 8, nseq), blk, 0, stream>>>(qkv, cu, attn);
    gemm8<0, 1><<<dim3((T + 255) / 256, 4), dim3(512), 0, stream>>>(
        attn, wo, bo, bo, bo, qn, kn, d_out, T, 1024, 1024);
  } else if (ws_size >= need_fall) {
    gemm_bt<1, 0><<<dim3((T + 127) / 128, 24), blk, 0, stream>>>(
        x, Wq, Wk, Wv, bq, bk, bv, qkv, T, 1024, 3072);
    rmsnorm_qk<<<dim3((2 * T * 256 + 255) / 256), blk, 0, stream>>>(qkv, qn, kn, T);
    attn_fwd<<<dim3(16, 8, nseq), blk, 0, stream>>>(qkv, cu, attn);
    gemm_bt<0, 1><<<dim3((T + 127) / 128, 8), blk, 0, stream>>>(
        attn, Wo, Wo, Wo, bo, bo, bo, d_out, T, 1024, 1024);
  } else {
    ws_too_small_sentinel<<<1, 64, 0, stream>>>((float*)d_out);
  }
}

// Round 7
// 272.522 us; speedup vs baseline: 1.0580x; 1.0580x over previous
//
#include <hip/hip_runtime.h>

typedef unsigned short u16;
typedef unsigned int   u32;

typedef __bf16 bf16x8_t __attribute__((ext_vector_type(8)));
typedef bf16x8_t bf16x8 __attribute__((may_alias));
typedef float f32x4_t __attribute__((ext_vector_type(4)));
typedef f32x4_t f32x4 __attribute__((may_alias));
typedef u32 u32x4_t __attribute__((ext_vector_type(4)));
typedef u32x4_t u32x4 __attribute__((may_alias));
typedef u32 u32x2_t __attribute__((ext_vector_type(2)));
typedef u32x2_t u32x2 __attribute__((may_alias));

__device__ __forceinline__ u16 f2b(float f) {        // RNE via hw cvt
  __bf16 h = (__bf16)f; u16 u; __builtin_memcpy(&u, &h, 2); return u;
}
__device__ __forceinline__ float b2f(u16 u) {
  u32 i = ((u32)u) << 16; float f; __builtin_memcpy(&f, &i, 4); return f;
}
__device__ __forceinline__ bf16x8_t cvt8(const float* p) {
  f32x4_t a = *(const f32x4*)p;
  f32x4_t b = *(const f32x4*)(p + 4);
  bf16x8_t v;
  v[0]=(__bf16)a[0]; v[1]=(__bf16)a[1]; v[2]=(__bf16)a[2]; v[3]=(__bf16)a[3];
  v[4]=(__bf16)b[0]; v[5]=(__bf16)b[1]; v[6]=(__bf16)b[2]; v[7]=(__bf16)b[3];
  return v;
}
// async global->LDS, 16B/lane (proper addrspacecast)
typedef __attribute__((address_space(1))) const void* as1cv;
typedef __attribute__((address_space(3))) void* as3v;
__device__ __forceinline__ void gld16(const u16* g, u16* l) {
  __builtin_amdgcn_global_load_lds((as1cv)g, (as3v)l, 16, 0, 0);
}

#define EPS 1.1920929e-07f

// ---------------------------------------------------------------------------
// cvt_pack: x (nx f32) + Wq|Wk|Wv|Wo (1M f32 each) -> bf16 blob (r10)
// ---------------------------------------------------------------------------
#define WSZ (1024 * 1024)
__global__ __launch_bounds__(256) void cvt_pack(
    const float* __restrict__ x, const float* __restrict__ wq,
    const float* __restrict__ wk, const float* __restrict__ wv,
    const float* __restrict__ wo, u16* __restrict__ dst, int nx)
{
  int idx4 = blockIdx.x * 256 + threadIdx.x;
  const int total4 = (nx + 4 * WSZ) >> 2;
  for (; idx4 < total4; idx4 += gridDim.x * 256) {
    int i = idx4 << 2;
    const float* src;
    if (i < nx) src = x + i;
    else {
      int o = i - nx;
      if      (o <     WSZ) src = wq + o;
      else if (o < 2 * WSZ) src = wk + o - WSZ;
      else if (o < 3 * WSZ) src = wv + o - 2 * WSZ;
      else                  src = wo + o - 3 * WSZ;
    }
    f32x4_t v = *(const f32x4*)src;
    u32x2_t p;
    p[0] = (u32)f2b(v[0]) | ((u32)f2b(v[1]) << 16);
    p[1] = (u32)f2b(v[2]) | ((u32)f2b(v[3]) << 16);
    *(u32x2*)(dst + i) = p;
  }
}

// ---------------------------------------------------------------------------
// gemm8 v2 (r13, resubmit -- r5 bench timed out at acquisition):
// 256x256 tile, BK=64, 512 threads (8 waves, 2Mx4N).
// Changes vs r12 (85us, regressed):
//  * IDENTITY block mapping (r12's chunked XCD swizzle made every XCD walk
//    ALL of A: FETCH 41->103MB. Identity round-robin pins 4 A-panels/XCD
//    across all n -- the old gemm_bt2 behavior, 41MB).
//  * COUNTED-vmcnt pipeline (the m218 lever; r12 drained vmcnt(0) per K-tile
//    via __syncthreads = "8-phase-with-drain0 == 1-phase"):
//      block k: issue kt k+1 stage (8 gld16, dbuf d^1)   [prev barrier
//               certified d^1's readers done]
//               s_waitcnt vmcnt(8)   [newest 8 = kt k+1 => kt k landed]
//               s_barrier            [landed for ALL waves]
//               4 phases {ds_read frags; setprio(1); 16 MFMA; setprio(0)}
//               s_waitcnt lgkmcnt(0); s_barrier   [readers done before next
//               block's writes into dbuf d]
//    vmcnt NEVER drains to 0 in the loop; each kt's loads get ~4 phases of
//    flight. All waits are asm volatile + "memory" (no compiler reorder).
//  * Swizzle kept verbatim (r12: bank conflicts 6.3M -> 0, refcheck'd):
//    LDS[r][c] = Gtile[r][c ^ (r&7)] via inverse-swizzled global source,
//    linear gld16 dest, swizzled frag read (both-sides, rule #21).
// ---------------------------------------------------------------------------
template<int NORM, int CF32>
__global__ __launch_bounds__(512, 2) void gemm8(
    const u16* __restrict__ A, const u16* __restrict__ Bm,
    const float* __restrict__ bias0, const float* __restrict__ bias1, const float* __restrict__ bias2,
    const float* __restrict__ qn, const float* __restrict__ kn,
    void* __restrict__ C, int M, int K, int ldc)
{
  __shared__ alignas(16) u16 lds[65536];     // 128 KB
  const int t = threadIdx.x;
  const int lane = t & 63, wave = t >> 6;
  const int quad = lane >> 4, col = lane & 15;
  const int wm = wave >> 2, wn = wave & 3;   // 2 M-halves x 4 N-quarters
  const int m0 = blockIdx.x * 256, n0 = blockIdx.y * 256;

  // staging geometry: thread t stages row srow=t>>3 (of a 64-row slice q),
  // 16B chunk (t&7); global source chunk pre-swizzled by ^(srow&7).
  const int srow = t >> 3;
  const int sx = ((t & 7) ^ (srow & 7)) << 3;          // u16 offset in 64-elem row
  const u16* asrc[2][2];
  const u16* bsrc[2][2];
#pragma unroll
  for (int h = 0; h < 2; ++h)
#pragma unroll
    for (int q = 0; q < 2; ++q) {
      int ar = m0 + h * 128 + q * 64 + srow; if (ar >= M) ar = M - 1;
      asrc[h][q] = A  + (size_t)ar * K + sx;
      int br = n0 + h * 128 + q * 64 + srow;           // N is exact multiple of 256
      bsrc[h][q] = Bm + (size_t)br * K + sx;
    }
  const int dst8 = t * 8;                              // u16 units, 16B/thread

#define STAGE(kt, db) do {                                               \
    const int koff_ = (kt) << 6;                                         \
    gld16(asrc[0][0] + koff_, lds + (2*(db)    ) * 8192 + dst8);         \
    gld16(asrc[0][1] + koff_, lds + (2*(db)    ) * 8192 + 4096 + dst8);  \
    gld16(asrc[1][0] + koff_, lds + (2*(db) + 1) * 8192 + dst8);         \
    gld16(asrc[1][1] + koff_, lds + (2*(db) + 1) * 8192 + 4096 + dst8);  \
    gld16(bsrc[0][0] + koff_, lds + 32768 + (2*(db)    ) * 8192 + dst8); \
    gld16(bsrc[0][1] + koff_, lds + 32768 + (2*(db)    ) * 8192 + 4096 + dst8); \
    gld16(bsrc[1][0] + koff_, lds + 32768 + (2*(db) + 1) * 8192 + dst8); \
    gld16(bsrc[1][1] + koff_, lds + 32768 + (2*(db) + 1) * 8192 + 4096 + dst8); \
  } while (0)

  STAGE(0, 0);                                         // prologue, no wait

  f32x4_t acc[8][4] = {};
  const int nt = K >> 6;
  for (int k = 0; k < nt; ++k) {
    const int d = k & 1;
    if (k + 1 < nt) {
      STAGE(k + 1, d ^ 1);
      asm volatile("s_waitcnt vmcnt(8)" ::: "memory");
    } else {
      asm volatile("s_waitcnt vmcnt(0)" ::: "memory");
    }
    asm volatile("s_barrier" ::: "memory");
    const u16* Ab = lds +         (2 * d + wm) * 8192;
    const u16* Bb = lds + 32768 + (2 * d + (wn >> 1)) * 8192;
    const int browb = ((wn & 1) * 64) << 6;            // B row base (u16 units)
    bf16x8 bfr[4];
#pragma unroll
    for (int p = 0; p < 4; ++p) {
      const int g = p & 1, ks = p >> 1;
      const int ck = (((ks * 4 + quad) ^ (col & 7)) << 3);
      if (g == 0) {
#pragma unroll
        for (int nj = 0; nj < 4; ++nj)
          bfr[nj] = *(const bf16x8*)(Bb + browb + ((nj * 16 + col) << 6) + ck);
      }
      bf16x8 af[4];
#pragma unroll
      for (int i = 0; i < 4; ++i)
        af[i] = *(const bf16x8*)(Ab + (((g * 4 + i) * 16 + col) << 6) + ck);
      __builtin_amdgcn_s_setprio(1);
#pragma unroll
      for (int i = 0; i < 4; ++i)
#pragma unroll
        for (int nj = 0; nj < 4; ++nj)
          acc[g * 4 + i][nj] = __builtin_amdgcn_mfma_f32_16x16x32_bf16(
              af[i], bfr[nj], acc[g * 4 + i][nj], 0, 0, 0);
      __builtin_amdgcn_s_setprio(0);
    }
    asm volatile("s_waitcnt lgkmcnt(0)" ::: "memory");
    asm volatile("s_barrier" ::: "memory");
  }
#undef STAGE

  // epilogue: bias + (optional) fused RMSNorm over the wave's 64-col head
  const int gnb = n0 + wn * 64;                        // 64-aligned head base
  const int seg = gnb >> 10, nl = gnb & 1023;
  const float* bias = seg == 0 ? bias0 : (seg == 1 ? bias1 : bias2);
  float bz[4], wz[4];
#pragma unroll
  for (int nj = 0; nj < 4; ++nj) {
    bz[nj] = bias[nl + nj * 16 + col];
    if (NORM) wz[nj] = (seg == 0 ? qn : kn)[nj * 16 + col];
  }
  const bool donorm = NORM && seg < 2;
#pragma unroll
  for (int mi = 0; mi < 8; ++mi) {
#pragma unroll
    for (int rr = 0; rr < 4; ++rr) {
      int gm = m0 + wm * 128 + mi * 16 + quad * 4 + rr;
      float v[4];
#pragma unroll
      for (int nj = 0; nj < 4; ++nj) v[nj] = acc[mi][nj][rr] + bz[nj];
      if (donorm) {
        float ss = v[0]*v[0] + v[1]*v[1] + v[2]*v[2] + v[3]*v[3];
        ss += __shfl_xor(ss, 1);
        ss += __shfl_xor(ss, 2);
        ss += __shfl_xor(ss, 4);
        ss += __shfl_xor(ss, 8);
        float sc = rsqrtf(ss * (1.0f / 64.0f) + EPS);
#pragma unroll
        for (int nj = 0; nj < 4; ++nj) v[nj] *= sc * wz[nj];
      }
      if (gm < M) {
#pragma unroll
        for (int nj = 0; nj < 4; ++nj) {
          int gn = gnb + nj * 16 + col;
          if (CF32) ((float*)C)[(size_t)gm * ldc + gn] = v[nj];
          else      ((u16*)C)[(size_t)gm * ldc + gn] = f2b(v[nj]);
        }
      }
    }
  }
}

// ---------------------------------------------------------------------------
// gemm_bt2 (r10, restored for the proj GEMM: 256^2 tiles only fill 128 of
// 256 CUs at N=1024; this 128^2 kernel keeps the chip full).
// ---------------------------------------------------------------------------
#define BK 32
template<int NORM, int CF32>
__global__ __launch_bounds__(256, 2) void gemm_bt2(
    const u16* __restrict__ A, const u16* __restrict__ Bm,
    const float* __restrict__ bias0, const float* __restrict__ bias1, const float* __restrict__ bias2,
    const float* __restrict__ qn, const float* __restrict__ kn,
    void* __restrict__ C, int M, int K, int ldc)
{
  __shared__ alignas(16) u16 As[128 * BK];
  __shared__ alignas(16) u16 Bs[128 * BK];
  const int t = threadIdx.x;
  const int lane = t & 63, wave = t >> 6;
  const int quad = lane >> 4, col = lane & 15;
  const int m0 = blockIdx.x * 128, n0 = blockIdx.y * 128;
  const int seg = n0 >> 10, nl0 = n0 & 1023;
  const float* bias = seg == 0 ? bias0 : (seg == 1 ? bias1 : bias2);
  const int wm = (wave >> 1) * 64, wn = (wave & 1) * 64;

  const int lrow = t >> 2;
  const int lcol = (t & 3) * 8;
  const u16* ga0 = A  + (size_t)(m0 + lrow) * K + lcol;
  const u16* ga1 = A  + (size_t)(m0 + 64 + lrow) * K + lcol;
  const u16* gb0 = Bm + (size_t)(n0 + lrow) * K + lcol;
  const u16* gb1 = Bm + (size_t)(n0 + 64 + lrow) * K + lcol;
  u16* lA0 = As + t * 8;
  u16* lA1 = As + 64 * BK + t * 8;
  u16* lB0 = Bs + t * 8;
  u16* lB1 = Bs + 64 * BK + t * 8;

  f32x4_t acc[4][4] = {};
  for (int k0 = 0; k0 < K; k0 += BK) {
    __syncthreads();
    gld16(ga0 + k0, lA0);
    gld16(ga1 + k0, lA1);
    gld16(gb0 + k0, lB0);
    gld16(gb1 + k0, lB1);
    __syncthreads();
    bf16x8 af[4], bfr[4];
#pragma unroll
    for (int i = 0; i < 4; ++i) {
      af[i]  = *(const bf16x8*)(As + (wm + i * 16 + col) * BK + quad * 8);
      bfr[i] = *(const bf16x8*)(Bs + (wn + i * 16 + col) * BK + quad * 8);
    }
#pragma unroll
    for (int i = 0; i < 4; ++i)
#pragma unroll
      for (int j = 0; j < 4; ++j)
        acc[i][j] = __builtin_amdgcn_mfma_f32_16x16x32_bf16(af[i], bfr[j], acc[i][j], 0, 0, 0);
  }

  float bz[4], wz[4];
#pragma unroll
  for (int j = 0; j < 4; ++j) {
    bz[j] = bias[nl0 + wn + j * 16 + col];
    if (NORM) wz[j] = (seg == 0 ? qn : kn)[j * 16 + col];
  }
  const bool donorm = NORM && seg < 2;
#pragma unroll
  for (int i = 0; i < 4; ++i) {
#pragma unroll
    for (int rr = 0; rr < 4; ++rr) {
      int gm = m0 + wm + i * 16 + quad * 4 + rr;
      float v[4];
#pragma unroll
      for (int j = 0; j < 4; ++j) v[j] = acc[i][j][rr] + bz[j];
      if (donorm) {
        float ss = v[0]*v[0] + v[1]*v[1] + v[2]*v[2] + v[3]*v[3];
        ss += __shfl_xor(ss, 1);
        ss += __shfl_xor(ss, 2);
        ss += __shfl_xor(ss, 4);
        ss += __shfl_xor(ss, 8);
        float sc = rsqrtf(ss * (1.0f / 64.0f) + EPS);
#pragma unroll
        for (int j = 0; j < 4; ++j) v[j] *= sc * wz[j];
      }
      if (gm < M) {
#pragma unroll
        for (int j = 0; j < 4; ++j) {
          int gn = n0 + wn + j * 16 + col;
          if (CF32) ((float*)C)[(size_t)gm * ldc + gn] = v[j];
          else      ((u16*)C)[(size_t)gm * ldc + gn] = f2b(v[j]);
        }
      }
    }
  }
}

// ---------------------------------------------------------------------------
// FALLBACK tier kernels (r9, unchanged)
// ---------------------------------------------------------------------------
template<int AF32, int CF32>
__global__ __launch_bounds__(256, 2) void gemm_bt(
    const void* __restrict__ Av,
    const float* __restrict__ B0, const float* __restrict__ B1, const float* __restrict__ B2,
    const float* __restrict__ bias0, const float* __restrict__ bias1, const float* __restrict__ bias2,
    void* __restrict__ C, int M, int K, int ldc)
{
  __shared__ alignas(16) u16 As[128 * BK];
  __shared__ alignas(16) u16 Bs[128 * BK];
  const int t = threadIdx.x;
  const int lane = t & 63, wave = t >> 6;
  const int quad = lane >> 4, col = lane & 15;
  const int m0 = blockIdx.x * 128, n0 = blockIdx.y * 128;
  const int seg = n0 >> 10;
  const float* B    = seg == 0 ? B0    : (seg == 1 ? B1    : B2);
  const float* bias = seg == 0 ? bias0 : (seg == 1 ? bias1 : bias2);
  const int nl0 = n0 & 1023;
  const int wm = (wave >> 1) * 64, wn = (wave & 1) * 64;
  const int lrow = t >> 2;
  const int lcol = (t & 3) * 8;
  int ar0 = m0 + lrow;      if (ar0 >= M) ar0 = M - 1;
  int ar1 = m0 + 64 + lrow; if (ar1 >= M) ar1 = M - 1;
  const float* bp0 = B + (size_t)(nl0 + lrow) * K + lcol;
  const float* bp1 = B + (size_t)(nl0 + 64 + lrow) * K + lcol;
  const float* apf0 = (const float*)Av + (size_t)ar0 * K + lcol;
  const float* apf1 = (const float*)Av + (size_t)ar1 * K + lcol;
  const u16*   aph0 = (const u16*)Av   + (size_t)ar0 * K + lcol;
  const u16*   aph1 = (const u16*)Av   + (size_t)ar1 * K + lcol;
  u16* lA0 = As + t * 8;
  u16* lA1 = As + 64 * BK + t * 8;
  u16* lB0 = Bs + t * 8;
  u16* lB1 = Bs + 64 * BK + t * 8;

  f32x4_t acc[4][4] = {};
  for (int k0 = 0; k0 < K; k0 += BK) {
    bf16x8_t va0, va1, vb0, vb1;
    if (AF32) { va0 = cvt8(apf0 + k0); va1 = cvt8(apf1 + k0); }
    else {
      u32x4_t r0 = *(const u32x4*)(aph0 + k0);
      u32x4_t r1 = *(const u32x4*)(aph1 + k0);
      __builtin_memcpy(&va0, &r0, 16);
      __builtin_memcpy(&va1, &r1, 16);
    }
    vb0 = cvt8(bp0 + k0);
    vb1 = cvt8(bp1 + k0);
    __syncthreads();
    *(bf16x8*)lA0 = va0; *(bf16x8*)lA1 = va1;
    *(bf16x8*)lB0 = vb0; *(bf16x8*)lB1 = vb1;
    __syncthreads();
    bf16x8 af[4], bfr[4];
#pragma unroll
    for (int i = 0; i < 4; ++i) {
      af[i]  = *(const bf16x8*)(As + (wm + i * 16 + col) * BK + quad * 8);
      bfr[i] = *(const bf16x8*)(Bs + (wn + i * 16 + col) * BK + quad * 8);
    }
#pragma unroll
    for (int i = 0; i < 4; ++i)
#pragma unroll
      for (int j = 0; j < 4; ++j)
        acc[i][j] = __builtin_amdgcn_mfma_f32_16x16x32_bf16(af[i], bfr[j], acc[i][j], 0, 0, 0);
  }
#pragma unroll
  for (int j = 0; j < 4; ++j) {
    int gn = n0 + wn + j * 16 + col;
    float bz = bias[nl0 + wn + j * 16 + col];
#pragma unroll
    for (int i = 0; i < 4; ++i) {
#pragma unroll
      for (int rr = 0; rr < 4; ++rr) {
        int gm = m0 + wm + i * 16 + quad * 4 + rr;
        if (gm < M) {
          float v = acc[i][j][rr] + bz;
          if (CF32) ((float*)C)[(size_t)gm * ldc + gn] = v;
          else      ((u16*)C)[(size_t)gm * ldc + gn] = f2b(v);
        }
      }
    }
  }
}

__global__ __launch_bounds__(256) void rmsnorm_qk(
    u16* __restrict__ qkv, const float* __restrict__ qn, const float* __restrict__ kn, int T)
{
  int gid = blockIdx.x * 256 + threadIdx.x;
  int row = gid >> 4, sub = gid & 15;
  if (row >= 2 * T * 16) return;
  int which = row >= T * 16;
  int r = which ? row - T * 16 : row;
  int tok = r >> 4, head = r & 15;
  u16* p = qkv + (size_t)tok * 3072 + which * 1024 + head * 64 + sub * 4;
  u16 d0 = p[0], d1 = p[1], d2 = p[2], d3 = p[3];
  float f0 = b2f(d0), f1 = b2f(d1), f2v = b2f(d2), f3 = b2f(d3);
  float ss = f0 * f0 + f1 * f1 + f2v * f2v + f3 * f3;
  ss += __shfl_xor(ss, 1);
  ss += __shfl_xor(ss, 2);
  ss += __shfl_xor(ss, 4);
  ss += __shfl_xor(ss, 8);
  float sc = rsqrtf(ss * (1.0f / 64.0f) + EPS);
  const float* w = which ? kn : qn;
  p[0] = f2b(f0 * sc * w[sub * 4 + 0]);
  p[1] = f2b(f1 * sc * w[sub * 4 + 1]);
  p[2] = f2b(f2v * sc * w[sub * 4 + 2]);
  p[3] = f2b(f3 * sc * w[sub * 4 + 3]);
}

// ---------------------------------------------------------------------------
// Flash attention v6 (r4-verified win: 110 -> ~75 us): HEAD-MAJOR grid,
// id%8 == head%8 -> XCD balance + K/V L2 reuse across qt. Unchanged.
// ---------------------------------------------------------------------------
#define SKS 68
#define SVS 68
#define SPS 68
__global__ __launch_bounds__(256, 4) void attn_fwd(
    const u16* __restrict__ qkv, const int* __restrict__ cu, u16* __restrict__ out)
{
  __shared__ alignas(16) u16 Ks[64 * SKS];
  __shared__ alignas(16) u16 Vts[64 * SVS];
  __shared__ alignas(16) u16 Ps[8 * 16 * SPS];   // 4 waves x 2 row-sets
  const int seq = blockIdx.z, head = blockIdx.x, qt = blockIdx.y;
  const int start = cu[seq], len = cu[seq + 1] - start;
  const int q0 = qt * 128;
  if (q0 >= len) return;
  const int t = threadIdx.x;
  const int lane = t & 63, wave = t >> 6, quad = lane >> 4, col = lane & 15;

  const int rA = q0 + wave * 16 + col, rB = rA + 64;
  const u16* qpA = qkv + (size_t)(start + (rA < len ? rA : len - 1)) * 3072 + head * 64 + quad * 8;
  const u16* qpB = qkv + (size_t)(start + (rB < len ? rB : len - 1)) * 3072 + head * 64 + quad * 8;
  bf16x8 qfA0 = *(const bf16x8*)qpA;
  bf16x8 qfA1 = *(const bf16x8*)(qpA + 32);
  bf16x8 qfB0 = *(const bf16x8*)qpB;
  bf16x8 qfB1 = *(const bf16x8*)(qpB + 32);

  f32x4_t accOA[4] = {}, accOB[4] = {};
  float lA[4] = {}, lB[4] = {};                  // per-lane partial row sums
  const float SC = 0.125f * 1.44269504089f;

  // staging (r11): sp=t>>3 -> (kc,kh); dc=t&7; key pair (keyA, keyA+16)
  const int sp = t >> 3, dc = t & 7;
  const int kc = sp & 15, kh = sp >> 4;
  const int keyA = kc + 32 * kh;
  u16* ksA = Ks + keyA * SKS + dc * 8;
  u16* ksB = Ks + (keyA + 16) * SKS + dc * 8;
  const int vcol = kc * 4 + 2 * kh;
  const size_t kvbase = 1024 + head * 64 + dc * 8;

  const int nkv = (len + 63) >> 6;
  u32x4_t rkA, rkB, rvA, rvB;
  {   // prologue: tile 0
    int ta = start + (keyA      < len ? keyA      : len - 1);
    int tb = start + (keyA + 16 < len ? keyA + 16 : len - 1);
    const u16* pa = qkv + (size_t)ta * 3072 + kvbase;
    const u16* pb2 = qkv + (size_t)tb * 3072 + kvbase;
    rkA = *(const u32x4*)pa;   rvA = *(const u32x4*)(pa + 1024);
    rkB = *(const u32x4*)pb2;  rvB = *(const u32x4*)(pb2 + 1024);
  }

  for (int it = 0; it < nkv; ++it) {
    const int k0 = it << 6;
    __syncthreads();
    *(u32x4*)ksA = rkA;
    *(u32x4*)ksB = rkB;
    {
      const u16* a = (const u16*)&rvA;
      const u16* b = (const u16*)&rvB;
#pragma unroll
      for (int j = 0; j < 8; ++j) {
        u32 pk = (u32)a[j] | ((u32)b[j] << 16);
        *(u32*)(Vts + (dc * 8 + j) * SVS + vcol) = pk;
      }
    }
    __syncthreads();
    if (it + 1 < nkv) {                          // prefetch next tile
      int kb0 = k0 + 64;
      int ta = start + (kb0 + keyA      < len ? kb0 + keyA      : len - 1);
      int tb = start + (kb0 + keyA + 16 < len ? kb0 + keyA + 16 : len - 1);
      const u16* pa = qkv + (size_t)ta * 3072 + kvbase;
      const u16* pb2 = qkv + (size_t)tb * 3072 + kvbase;
      rkA = *(const u32x4*)pa;   rvA = *(const u32x4*)(pa + 1024);
      rkB = *(const u32x4*)pb2;  rvB = *(const u32x4*)(pb2 + 1024);
    }

    // S = Q.K^T for both row sets (independent chains)
    f32x4_t sgA[4], sgB[4];
#pragma unroll
    for (int g = 0; g < 4; ++g) {
      bf16x8 kb0 = *(const bf16x8*)(Ks + (g*16 + col) * SKS + quad * 8);
      bf16x8 kb1 = *(const bf16x8*)(Ks + (g*16 + col) * SKS + 32 + quad * 8);
      f32x4_t sA = {}, sB = {};
      sA = __builtin_amdgcn_mfma_f32_16x16x32_bf16(qfA0, kb0, sA, 0, 0, 0);
      sB = __builtin_amdgcn_mfma_f32_16x16x32_bf16(qfB0, kb0, sB, 0, 0, 0);
      sA = __builtin_amdgcn_mfma_f32_16x16x32_bf16(qfA1, kb1, sA, 0, 0, 0);
      sB = __builtin_amdgcn_mfma_f32_16x16x32_bf16(qfB1, kb1, sB, 0, 0, 0);
      sgA[g] = sA; sgB[g] = sB;
    }

    // P = exp2(S*SC), masked; key g*16+col -> column col*4+g (b64 rows)
    // L partials accumulate in-register from the SAME rounded bf16 values.
    const bool full = (k0 + 64 <= len);
    bool vg[4];
#pragma unroll
    for (int g = 0; g < 4; ++g) vg[g] = full || (k0 + g*16 + col) < len;
    u16* pwA = Ps + wave * (16 * SPS);
    u16* pwB = Ps + (4 + wave) * (16 * SPS);
#pragma unroll
    for (int r = 0; r < 4; ++r) {
      u16 peA[4], peB[4];
#pragma unroll
      for (int g = 0; g < 4; ++g) {
        float pA = exp2f(sgA[g][r] * SC);
        float pB = exp2f(sgB[g][r] * SC);
        peA[g] = vg[g] ? f2b(pA) : (u16)0;
        peB[g] = vg[g] ? f2b(pB) : (u16)0;
      }
      lA[r] += (b2f(peA[0]) + b2f(peA[1])) + (b2f(peA[2]) + b2f(peA[3]));
      lB[r] += (b2f(peB[0]) + b2f(peB[1])) + (b2f(peB[2]) + b2f(peB[3]));
      u32x2_t wA, wB;
      wA[0] = (u32)peA[0] | ((u32)peA[1] << 16);
      wA[1] = (u32)peA[2] | ((u32)peA[3] << 16);
      wB[0] = (u32)peB[0] | ((u32)peB[1] << 16);
      wB[1] = (u32)peB[2] | ((u32)peB[3] << 16);
      *(u32x2*)(pwA + (quad*4 + r) * SPS + col * 4) = wA;
      *(u32x2*)(pwB + (quad*4 + r) * SPS + col * 4) = wB;
    }
    __threadfence_block();

    bf16x8 pfA0 = *(const bf16x8*)(pwA + col * SPS + quad * 8);
    bf16x8 pfA1 = *(const bf16x8*)(pwA + col * SPS + 32 + quad * 8);
    bf16x8 pfB0 = *(const bf16x8*)(pwB + col * SPS + quad * 8);
    bf16x8 pfB1 = *(const bf16x8*)(pwB + col * SPS + 32 + quad * 8);
#pragma unroll
    for (int c = 0; c < 4; ++c) {
      bf16x8 vf0 = *(const bf16x8*)(Vts + (c*16 + col) * SVS + quad * 8);
      bf16x8 vf1 = *(const bf16x8*)(Vts + (c*16 + col) * SVS + 32 + quad * 8);
      accOA[c] = __builtin_amdgcn_mfma_f32_16x16x32_bf16(pfA0, vf0, accOA[c], 0, 0, 0);
      accOB[c] = __builtin_amdgcn_mfma_f32_16x16x32_bf16(pfB0, vf0, accOB[c], 0, 0, 0);
      accOA[c] = __builtin_amdgcn_mfma_f32_16x16x32_bf16(pfA1, vf1, accOA[c], 0, 0, 0);
      accOB[c] = __builtin_amdgcn_mfma_f32_16x16x32_bf16(pfB1, vf1, accOB[c], 0, 0, 0);
    }
  }

  // epilogue: finish L reduction across the 16 lanes sharing a quad
#pragma unroll
  for (int r = 0; r < 4; ++r) {
    float sA = lA[r], sB = lB[r];
    sA += __shfl_xor(sA, 1); sB += __shfl_xor(sB, 1);
    sA += __shfl_xor(sA, 2); sB += __shfl_xor(sB, 2);
    sA += __shfl_xor(sA, 4); sB += __shfl_xor(sB, 4);
    sA += __shfl_xor(sA, 8); sB += __shfl_xor(sB, 8);
    int rowA = q0 + wave * 16 + quad * 4 + r;
    int rowB = rowA + 64;
    if (rowA < len) {
      float inv = 1.0f / sA;
      u16* op = out + (size_t)(start + rowA) * 1024 + head * 64 + col;
      op[0]  = f2b(accOA[0][r] * inv);
      op[16] = f2b(accOA[1][r] * inv);
      op[32] = f2b(accOA[2][r] * inv);
      op[48] = f2b(accOA[3][r] * inv);
    }
    if (rowB < len) {
      float inv = 1.0f / sB;
      u16* op = out + (size_t)(start + rowB) * 1024 + head * 64 + col;
      op[0]  = f2b(accOB[0][r] * inv);
      op[16] = f2b(accOB[1][r] * inv);
      op[32] = f2b(accOB[2][r] * inv);
      op[48] = f2b(accOB[3][r] * inv);
    }
  }
}

__global__ void ws_too_small_sentinel(float* out) {
  if (threadIdx.x == 0 && blockIdx.x == 0) out[0] = 1024.0f;
}

// ---------------------------------------------------------------------------
extern "C" void kernel_launch(void* const* d_in, const int* in_sizes, int n_in,
                              void* d_out, int out_size, void* d_ws, size_t ws_size,
                              hipStream_t stream) {
  const float* x  = (const float*)d_in[0];
  const int*   cu = (const int*)d_in[1];
  const float* Wq = (const float*)d_in[2];
  const float* bq = (const float*)d_in[3];
  const float* Wk = (const float*)d_in[4];
  const float* bk = (const float*)d_in[5];
  const float* Wv = (const float*)d_in[6];
  const float* bv = (const float*)d_in[7];
  const float* qn = (const float*)d_in[8];
  const float* kn = (const float*)d_in[9];
  const float* Wo = (const float*)d_in[10];
  const float* bo = (const float*)d_in[11];

  const int T = in_sizes[0] / 1024;
  const int nseq = in_sizes[1] - 1;

  const size_t need_fast = ((size_t)T * 5120 + 4 * WSZ) * 2;   // 92.3 MB @ T=8192
  const size_t need_fall = (size_t)T * 4096 * 2;               // 67.1 MB

  u16* qkv  = (u16*)d_ws;
  u16* attn = qkv + (size_t)T * 3072;
  dim3 blk(256);

  if (ws_size >= need_fast) {
    u16* xb   = attn + (size_t)T * 1024;
    u16* wqkv = xb + (size_t)T * 1024;
    u16* wo   = wqkv + 3 * WSZ;
    cvt_pack<<<dim3(1024), blk, 0, stream>>>(x, Wq, Wk, Wv, Wo, xb, T * 1024);
    gemm8<1, 0><<<dim3((T + 255) / 256, 12), dim3(512), 0, stream>>>(
        xb, wqkv, bq, bk, bv, qn, kn, qkv, T, 1024, 3072);
    attn_fwd<<<dim3(16, 8, nseq), blk, 0, stream>>>(qkv, cu, attn);
    gemm_bt2<0, 1><<<dim3((T + 127) / 128, 8), blk, 0, stream>>>(
        attn, wo, bo, bo, bo, qn, kn, d_out, T, 1024, 1024);
  } else if (ws_size >= need_fall) {
    gemm_bt<1, 0><<<dim3((T + 127) / 128, 24), blk, 0, stream>>>(
        x, Wq, Wk, Wv, bq, bk, bv, qkv, T, 1024, 3072);
    rmsnorm_qk<<<dim3((2 * T * 256 + 255) / 256), blk, 0, stream>>>(qkv, qn, kn, T);
    attn_fwd<<<dim3(16, 8, nseq), blk, 0, stream>>>(qkv, cu, attn);
    gemm_bt<0, 1><<<dim3((T + 127) / 128, 8), blk, 0, stream>>>(
        attn, Wo, Wo, Wo, bo, bo, bo, d_out, T, 1024, 1024);
  } else {
    ws_too_small_sentinel<<<1, 64, 0, stream>>>((float*)d_out);
  }
}

// Round 12
// 271.307 us; speedup vs baseline: 1.0627x; 1.0045x over previous
//
#include <hip/hip_runtime.h>

typedef unsigned short u16;
typedef unsigned int   u32;

typedef __bf16 bf16x8_t __attribute__((ext_vector_type(8)));
typedef bf16x8_t bf16x8 __attribute__((may_alias));
typedef float f32x4_t __attribute__((ext_vector_type(4)));
typedef f32x4_t f32x4 __attribute__((may_alias));
typedef u32 u32x4_t __attribute__((ext_vector_type(4)));
typedef u32x4_t u32x4 __attribute__((may_alias));
typedef u32 u32x2_t __attribute__((ext_vector_type(2)));
typedef u32x2_t u32x2 __attribute__((may_alias));

__device__ __forceinline__ u16 f2b(float f) {        // RNE via hw cvt
  __bf16 h = (__bf16)f; u16 u; __builtin_memcpy(&u, &h, 2); return u;
}
__device__ __forceinline__ float b2f(u16 u) {
  u32 i = ((u32)u) << 16; float f; __builtin_memcpy(&f, &i, 4); return f;
}
__device__ __forceinline__ bf16x8_t cvt8(const float* p) {
  f32x4_t a = *(const f32x4*)p;
  f32x4_t b = *(const f32x4*)(p + 4);
  bf16x8_t v;
  v[0]=(__bf16)a[0]; v[1]=(__bf16)a[1]; v[2]=(__bf16)a[2]; v[3]=(__bf16)a[3];
  v[4]=(__bf16)b[0]; v[5]=(__bf16)b[1]; v[6]=(__bf16)b[2]; v[7]=(__bf16)b[3];
  return v;
}
// async global->LDS, 16B/lane (proper addrspacecast)
typedef __attribute__((address_space(1))) const void* as1cv;
typedef __attribute__((address_space(3))) void* as3v;
__device__ __forceinline__ void gld16(const u16* g, u16* l) {
  __builtin_amdgcn_global_load_lds((as1cv)g, (as3v)l, 16, 0, 0);
}

#define EPS 1.1920929e-07f

// ---------------------------------------------------------------------------
// cvt_pack: x (nx f32) + Wq|Wk|Wv|Wo (1M f32 each) -> bf16 blob (r10)
// ---------------------------------------------------------------------------
#define WSZ (1024 * 1024)
__global__ __launch_bounds__(256) void cvt_pack(
    const float* __restrict__ x, const float* __restrict__ wq,
    const float* __restrict__ wk, const float* __restrict__ wv,
    const float* __restrict__ wo, u16* __restrict__ dst, int nx)
{
  int idx4 = blockIdx.x * 256 + threadIdx.x;
  const int total4 = (nx + 4 * WSZ) >> 2;
  for (; idx4 < total4; idx4 += gridDim.x * 256) {
    int i = idx4 << 2;
    const float* src;
    if (i < nx) src = x + i;
    else {
      int o = i - nx;
      if      (o <     WSZ) src = wq + o;
      else if (o < 2 * WSZ) src = wk + o - WSZ;
      else if (o < 3 * WSZ) src = wv + o - 2 * WSZ;
      else                  src = wo + o - 3 * WSZ;
    }
    f32x4_t v = *(const f32x4*)src;
    u32x2_t p;
    p[0] = (u32)f2b(v[0]) | ((u32)f2b(v[1]) << 16);
    p[1] = (u32)f2b(v[2]) | ((u32)f2b(v[3]) << 16);
    *(u32x2*)(dst + i) = p;
  }
}

// ---------------------------------------------------------------------------
// gemm8 v3 (r14, 5th submit -- r7-r10 benches timed out at acquisition):
// same 256x256/BK=64/8-wave geometry + swizzle as v2 (refcheck'd r5/r7;
// conflicts=0, FETCH=41MB), but the sync structure is the m196/m201
// PER-PHASE INTERLEAVE -- the piece both prior attempts lacked:
//   v1 (r12, 85us): drain vmcnt(0)/K-tile  -> "8-phase-with-drain0 == 1-phase"
//   v2 (r13, 79us): counted vmcnt but all 8 stages in one burst + barrier-free
//                   phases -> m196's proven loser (-7..-27% vs interleave)
// v3 per K-tile k (dbuf d=k&1):
//   boundary: STAGE ht0 of kt k+1 -> dbuf d^1   [readers of d^1 done at kt
//             k-1's closing barrier]
//             s_waitcnt vmcnt(2)  [10 outstanding - 2 newest = kt k's 8
//             landed; NEVER drains to 0 mid-loop]
//             s_barrier
//   phase p=0..3: ds_read frags (A 4xb128; B +4 at p0/p2)
//                 STAGE ht p of kt k+1 (p>=1)
//                 s_barrier; s_waitcnt lgkmcnt(0); sched_barrier(0) [rule 18]
//                 setprio(1); 16 MFMA; setprio(0); s_barrier (p<3)
//   closing: s_barrier  [certifies dbuf d readers done]
// Ledger: stages only ever target dbuf d^1 (no write-under-read); outstanding
// is exactly 8 at every boundary; steady state holds from k=0 (prologue = 8).
// PRE-COMMITTED EXIT (r12): win -> keep; neutral/loser/timeout/fail -> revert
// QKV to gemm_bt2 and close this lane.
// ---------------------------------------------------------------------------
template<int NORM, int CF32>
__global__ __launch_bounds__(512, 2) void gemm8(
    const u16* __restrict__ A, const u16* __restrict__ Bm,
    const float* __restrict__ bias0, const float* __restrict__ bias1, const float* __restrict__ bias2,
    const float* __restrict__ qn, const float* __restrict__ kn,
    void* __restrict__ C, int M, int K, int ldc)
{
  __shared__ alignas(16) u16 lds[65536];     // 128 KB
  const int t = threadIdx.x;
  const int lane = t & 63, wave = t >> 6;
  const int quad = lane >> 4, col = lane & 15;
  const int wm = wave >> 2, wn = wave & 3;   // 2 M-halves x 4 N-quarters
  const int m0 = blockIdx.x * 256, n0 = blockIdx.y * 256;

  // staging geometry: thread t stages row srow=t>>3 (of a 64-row slice q),
  // 16B chunk (t&7); global source chunk pre-swizzled by ^(srow&7).
  const int srow = t >> 3;
  const int sx = ((t & 7) ^ (srow & 7)) << 3;          // u16 offset in 64-elem row
  const u16* asrc[2][2];
  const u16* bsrc[2][2];
#pragma unroll
  for (int h = 0; h < 2; ++h)
#pragma unroll
    for (int q = 0; q < 2; ++q) {
      int ar = m0 + h * 128 + q * 64 + srow; if (ar >= M) ar = M - 1;
      asrc[h][q] = A  + (size_t)ar * K + sx;
      int br = n0 + h * 128 + q * 64 + srow;           // N is exact multiple of 256
      bsrc[h][q] = Bm + (size_t)br * K + sx;
    }
  const int dst8 = t * 8;                              // u16 units, 16B/thread

  // half-tile stage: ht 0=A-half0, 1=A-half1, 2=B-half0, 3=B-half1 (2 gld16)
#define STAGE_HT(kt, db, ht) do {                                          \
    const int koff_ = (kt) << 6;                                           \
    if ((ht) == 0) {                                                       \
      gld16(asrc[0][0] + koff_, lds + (2*(db)    ) * 8192 + dst8);         \
      gld16(asrc[0][1] + koff_, lds + (2*(db)    ) * 8192 + 4096 + dst8);  \
    } else if ((ht) == 1) {                                                \
      gld16(asrc[1][0] + koff_, lds + (2*(db) + 1) * 8192 + dst8);         \
      gld16(asrc[1][1] + koff_, lds + (2*(db) + 1) * 8192 + 4096 + dst8);  \
    } else if ((ht) == 2) {                                                \
      gld16(bsrc[0][0] + koff_, lds + 32768 + (2*(db)    ) * 8192 + dst8); \
      gld16(bsrc[0][1] + koff_, lds + 32768 + (2*(db)    ) * 8192 + 4096 + dst8); \
    } else {                                                               \
      gld16(bsrc[1][0] + koff_, lds + 32768 + (2*(db) + 1) * 8192 + dst8); \
      gld16(bsrc[1][1] + koff_, lds + 32768 + (2*(db) + 1) * 8192 + 4096 + dst8); \
    }                                                                      \
  } while (0)

  // prologue: all 4 half-tiles of kt0 into dbuf0 (8 loads, no wait yet)
  STAGE_HT(0, 0, 0); STAGE_HT(0, 0, 1); STAGE_HT(0, 0, 2); STAGE_HT(0, 0, 3);

  f32x4_t acc[8][4] = {};
  const int nt = K >> 6;
  for (int k = 0; k < nt; ++k) {
    const int d = k & 1;
    const bool pf = (k + 1 < nt);
    if (pf) {
      STAGE_HT(k + 1, d ^ 1, 0);
      asm volatile("s_waitcnt vmcnt(2)" ::: "memory");
    } else {
      asm volatile("s_waitcnt vmcnt(0)" ::: "memory");
    }
    asm volatile("s_barrier" ::: "memory");
    const u16* Ab = lds +         (2 * d + wm) * 8192;
    const u16* Bb = lds + 32768 + (2 * d + (wn >> 1)) * 8192;
    const int browb = ((wn & 1) * 64) << 6;            // B row base (u16 units)
    bf16x8 bfr[4];
#pragma unroll
    for (int p = 0; p < 4; ++p) {
      const int g = p & 1, ks = p >> 1;
      const int ck = (((ks * 4 + quad) ^ (col & 7)) << 3);
      if (g == 0) {
#pragma unroll
        for (int nj = 0; nj < 4; ++nj)
          bfr[nj] = *(const bf16x8*)(Bb + browb + ((nj * 16 + col) << 6) + ck);
      }
      bf16x8 af[4];
#pragma unroll
      for (int i = 0; i < 4; ++i)
        af[i] = *(const bf16x8*)(Ab + (((g * 4 + i) * 16 + col) << 6) + ck);
      if (p >= 1 && pf) STAGE_HT(k + 1, d ^ 1, p);
      asm volatile("s_barrier" ::: "memory");
      asm volatile("s_waitcnt lgkmcnt(0)" ::: "memory");
      __builtin_amdgcn_sched_barrier(0);
      __builtin_amdgcn_s_setprio(1);
#pragma unroll
      for (int i = 0; i < 4; ++i)
#pragma unroll
        for (int nj = 0; nj < 4; ++nj)
          acc[g * 4 + i][nj] = __builtin_amdgcn_mfma_f32_16x16x32_bf16(
              af[i], bfr[nj], acc[g * 4 + i][nj], 0, 0, 0);
      __builtin_amdgcn_s_setprio(0);
      if (p < 3) asm volatile("s_barrier" ::: "memory");
    }
    asm volatile("s_barrier" ::: "memory");   // closing: dbuf d readers done
  }
#undef STAGE_HT

  // epilogue: bias + (optional) fused RMSNorm over the wave's 64-col head
  const int gnb = n0 + wn * 64;                        // 64-aligned head base
  const int seg = gnb >> 10, nl = gnb & 1023;
  const float* bias = seg == 0 ? bias0 : (seg == 1 ? bias1 : bias2);
  float bz[4], wz[4];
#pragma unroll
  for (int nj = 0; nj < 4; ++nj) {
    bz[nj] = bias[nl + nj * 16 + col];
    if (NORM) wz[nj] = (seg == 0 ? qn : kn)[nj * 16 + col];
  }
  const bool donorm = NORM && seg < 2;
#pragma unroll
  for (int mi = 0; mi < 8; ++mi) {
#pragma unroll
    for (int rr = 0; rr < 4; ++rr) {
      int gm = m0 + wm * 128 + mi * 16 + quad * 4 + rr;
      float v[4];
#pragma unroll
      for (int nj = 0; nj < 4; ++nj) v[nj] = acc[mi][nj][rr] + bz[nj];
      if (donorm) {
        float ss = v[0]*v[0] + v[1]*v[1] + v[2]*v[2] + v[3]*v[3];
        ss += __shfl_xor(ss, 1);
        ss += __shfl_xor(ss, 2);
        ss += __shfl_xor(ss, 4);
        ss += __shfl_xor(ss, 8);
        float sc = rsqrtf(ss * (1.0f / 64.0f) + EPS);
#pragma unroll
        for (int nj = 0; nj < 4; ++nj) v[nj] *= sc * wz[nj];
      }
      if (gm < M) {
#pragma unroll
        for (int nj = 0; nj < 4; ++nj) {
          int gn = gnb + nj * 16 + col;
          if (CF32) ((float*)C)[(size_t)gm * ldc + gn] = v[nj];
          else      ((u16*)C)[(size_t)gm * ldc + gn] = f2b(v[nj]);
        }
      }
    }
  }
}

// ---------------------------------------------------------------------------
// gemm_bt2 (r10, kept for the proj GEMM; 75us measured on QKV shape r4).
// ---------------------------------------------------------------------------
#define BK 32
template<int NORM, int CF32>
__global__ __launch_bounds__(256, 2) void gemm_bt2(
    const u16* __restrict__ A, const u16* __restrict__ Bm,
    const float* __restrict__ bias0, const float* __restrict__ bias1, const float* __restrict__ bias2,
    const float* __restrict__ qn, const float* __restrict__ kn,
    void* __restrict__ C, int M, int K, int ldc)
{
  __shared__ alignas(16) u16 As[128 * BK];
  __shared__ alignas(16) u16 Bs[128 * BK];
  const int t = threadIdx.x;
  const int lane = t & 63, wave = t >> 6;
  const int quad = lane >> 4, col = lane & 15;
  const int m0 = blockIdx.x * 128, n0 = blockIdx.y * 128;
  const int seg = n0 >> 10, nl0 = n0 & 1023;
  const float* bias = seg == 0 ? bias0 : (seg == 1 ? bias1 : bias2);
  const int wm = (wave >> 1) * 64, wn = (wave & 1) * 64;

  const int lrow = t >> 2;
  const int lcol = (t & 3) * 8;
  const u16* ga0 = A  + (size_t)(m0 + lrow) * K + lcol;
  const u16* ga1 = A  + (size_t)(m0 + 64 + lrow) * K + lcol;
  const u16* gb0 = Bm + (size_t)(n0 + lrow) * K + lcol;
  const u16* gb1 = Bm + (size_t)(n0 + 64 + lrow) * K + lcol;
  u16* lA0 = As + t * 8;
  u16* lA1 = As + 64 * BK + t * 8;
  u16* lB0 = Bs + t * 8;
  u16* lB1 = Bs + 64 * BK + t * 8;

  f32x4_t acc[4][4] = {};
  for (int k0 = 0; k0 < K; k0 += BK) {
    __syncthreads();
    gld16(ga0 + k0, lA0);
    gld16(ga1 + k0, lA1);
    gld16(gb0 + k0, lB0);
    gld16(gb1 + k0, lB1);
    __syncthreads();
    bf16x8 af[4], bfr[4];
#pragma unroll
    for (int i = 0; i < 4; ++i) {
      af[i]  = *(const bf16x8*)(As + (wm + i * 16 + col) * BK + quad * 8);
      bfr[i] = *(const bf16x8*)(Bs + (wn + i * 16 + col) * BK + quad * 8);
    }
#pragma unroll
    for (int i = 0; i < 4; ++i)
#pragma unroll
      for (int j = 0; j < 4; ++j)
        acc[i][j] = __builtin_amdgcn_mfma_f32_16x16x32_bf16(af[i], bfr[j], acc[i][j], 0, 0, 0);
  }

  float bz[4], wz[4];
#pragma unroll
  for (int j = 0; j < 4; ++j) {
    bz[j] = bias[nl0 + wn + j * 16 + col];
    if (NORM) wz[j] = (seg == 0 ? qn : kn)[j * 16 + col];
  }
  const bool donorm = NORM && seg < 2;
#pragma unroll
  for (int i = 0; i < 4; ++i) {
#pragma unroll
    for (int rr = 0; rr < 4; ++rr) {
      int gm = m0 + wm + i * 16 + quad * 4 + rr;
      float v[4];
#pragma unroll
      for (int j = 0; j < 4; ++j) v[j] = acc[i][j][rr] + bz[j];
      if (donorm) {
        float ss = v[0]*v[0] + v[1]*v[1] + v[2]*v[2] + v[3]*v[3];
        ss += __shfl_xor(ss, 1);
        ss += __shfl_xor(ss, 2);
        ss += __shfl_xor(ss, 4);
        ss += __shfl_xor(ss, 8);
        float sc = rsqrtf(ss * (1.0f / 64.0f) + EPS);
#pragma unroll
        for (int j = 0; j < 4; ++j) v[j] *= sc * wz[j];
      }
      if (gm < M) {
#pragma unroll
        for (int j = 0; j < 4; ++j) {
          int gn = n0 + wn + j * 16 + col;
          if (CF32) ((float*)C)[(size_t)gm * ldc + gn] = v[j];
          else      ((u16*)C)[(size_t)gm * ldc + gn] = f2b(v[j]);
        }
      }
    }
  }
}

// ---------------------------------------------------------------------------
// FALLBACK tier kernels (r9, unchanged)
// ---------------------------------------------------------------------------
template<int AF32, int CF32>
__global__ __launch_bounds__(256, 2) void gemm_bt(
    const void* __restrict__ Av,
    const float* __restrict__ B0, const float* __restrict__ B1, const float* __restrict__ B2,
    const float* __restrict__ bias0, const float* __restrict__ bias1, const float* __restrict__ bias2,
    void* __restrict__ C, int M, int K, int ldc)
{
  __shared__ alignas(16) u16 As[128 * BK];
  __shared__ alignas(16) u16 Bs[128 * BK];
  const int t = threadIdx.x;
  const int lane = t & 63, wave = t >> 6;
  const int quad = lane >> 4, col = lane & 15;
  const int m0 = blockIdx.x * 128, n0 = blockIdx.y * 128;
  const int seg = n0 >> 10;
  const float* B    = seg == 0 ? B0    : (seg == 1 ? B1    : B2);
  const float* bias = seg == 0 ? bias0 : (seg == 1 ? bias1 : bias2);
  const int nl0 = n0 & 1023;
  const int wm = (wave >> 1) * 64, wn = (wave & 1) * 64;
  const int lrow = t >> 2;
  const int lcol = (t & 3) * 8;
  int ar0 = m0 + lrow;      if (ar0 >= M) ar0 = M - 1;
  int ar1 = m0 + 64 + lrow; if (ar1 >= M) ar1 = M - 1;
  const float* bp0 = B + (size_t)(nl0 + lrow) * K + lcol;
  const float* bp1 = B + (size_t)(nl0 + 64 + lrow) * K + lcol;
  const float* apf0 = (const float*)Av + (size_t)ar0 * K + lcol;
  const float* apf1 = (const float*)Av + (size_t)ar1 * K + lcol;
  const u16*   aph0 = (const u16*)Av   + (size_t)ar0 * K + lcol;
  const u16*   aph1 = (const u16*)Av   + (size_t)ar1 * K + lcol;
  u16* lA0 = As + t * 8;
  u16* lA1 = As + 64 * BK + t * 8;
  u16* lB0 = Bs + t * 8;
  u16* lB1 = Bs + 64 * BK + t * 8;

  f32x4_t acc[4][4] = {};
  for (int k0 = 0; k0 < K; k0 += BK) {
    bf16x8_t va0, va1, vb0, vb1;
    if (AF32) { va0 = cvt8(apf0 + k0); va1 = cvt8(apf1 + k0); }
    else {
      u32x4_t r0 = *(const u32x4*)(aph0 + k0);
      u32x4_t r1 = *(const u32x4*)(aph1 + k0);
      __builtin_memcpy(&va0, &r0, 16);
      __builtin_memcpy(&va1, &r1, 16);
    }
    vb0 = cvt8(bp0 + k0);
    vb1 = cvt8(bp1 + k0);
    __syncthreads();
    *(bf16x8*)lA0 = va0; *(bf16x8*)lA1 = va1;
    *(bf16x8*)lB0 = vb0; *(bf16x8*)lB1 = vb1;
    __syncthreads();
    bf16x8 af[4], bfr[4];
#pragma unroll
    for (int i = 0; i < 4; ++i) {
      af[i]  = *(const bf16x8*)(As + (wm + i * 16 + col) * BK + quad * 8);
      bfr[i] = *(const bf16x8*)(Bs + (wn + i * 16 + col) * BK + quad * 8);
    }
#pragma unroll
    for (int i = 0; i < 4; ++i)
#pragma unroll
      for (int j = 0; j < 4; ++j)
        acc[i][j] = __builtin_amdgcn_mfma_f32_16x16x32_bf16(af[i], bfr[j], acc[i][j], 0, 0, 0);
  }
#pragma unroll
  for (int j = 0; j < 4; ++j) {
    int gn = n0 + wn + j * 16 + col;
    float bz = bias[nl0 + wn + j * 16 + col];
#pragma unroll
    for (int i = 0; i < 4; ++i) {
#pragma unroll
      for (int rr = 0; rr < 4; ++rr) {
        int gm = m0 + wm + i * 16 + quad * 4 + rr;
        if (gm < M) {
          float v = acc[i][j][rr] + bz;
          if (CF32) ((float*)C)[(size_t)gm * ldc + gn] = v;
          else      ((u16*)C)[(size_t)gm * ldc + gn] = f2b(v);
        }
      }
    }
  }
}

__global__ __launch_bounds__(256) void rmsnorm_qk(
    u16* __restrict__ qkv, const float* __restrict__ qn, const float* __restrict__ kn, int T)
{
  int gid = blockIdx.x * 256 + threadIdx.x;
  int row = gid >> 4, sub = gid & 15;
  if (row >= 2 * T * 16) return;
  int which = row >= T * 16;
  int r = which ? row - T * 16 : row;
  int tok = r >> 4, head = r & 15;
  u16* p = qkv + (size_t)tok * 3072 + which * 1024 + head * 64 + sub * 4;
  u16 d0 = p[0], d1 = p[1], d2 = p[2], d3 = p[3];
  float f0 = b2f(d0), f1 = b2f(d1), f2v = b2f(d2), f3 = b2f(d3);
  float ss = f0 * f0 + f1 * f1 + f2v * f2v + f3 * f3;
  ss += __shfl_xor(ss, 1);
  ss += __shfl_xor(ss, 2);
  ss += __shfl_xor(ss, 4);
  ss += __shfl_xor(ss, 8);
  float sc = rsqrtf(ss * (1.0f / 64.0f) + EPS);
  const float* w = which ? kn : qn;
  p[0] = f2b(f0 * sc * w[sub * 4 + 0]);
  p[1] = f2b(f1 * sc * w[sub * 4 + 1]);
  p[2] = f2b(f2v * sc * w[sub * 4 + 2]);
  p[3] = f2b(f3 * sc * w[sub * 4 + 3]);
}

// ---------------------------------------------------------------------------
// Flash attention v6 (r4-verified win: 110 -> ~75 us): HEAD-MAJOR grid,
// id%8 == head%8 -> XCD balance + K/V L2 reuse across qt. Unchanged.
// ---------------------------------------------------------------------------
#define SKS 68
#define SVS 68
#define SPS 68
__global__ __launch_bounds__(256, 4) void attn_fwd(
    const u16* __restrict__ qkv, const int* __restrict__ cu, u16* __restrict__ out)
{
  __shared__ alignas(16) u16 Ks[64 * SKS];
  __shared__ alignas(16) u16 Vts[64 * SVS];
  __shared__ alignas(16) u16 Ps[8 * 16 * SPS];   // 4 waves x 2 row-sets
  const int seq = blockIdx.z, head = blockIdx.x, qt = blockIdx.y;
  const int start = cu[seq], len = cu[seq + 1] - start;
  const int q0 = qt * 128;
  if (q0 >= len) return;
  const int t = threadIdx.x;
  const int lane = t & 63, wave = t >> 6, quad = lane >> 4, col = lane & 15;

  const int rA = q0 + wave * 16 + col, rB = rA + 64;
  const u16* qpA = qkv + (size_t)(start + (rA < len ? rA : len - 1)) * 3072 + head * 64 + quad * 8;
  const u16* qpB = qkv + (size_t)(start + (rB < len ? rB : len - 1)) * 3072 + head * 64 + quad * 8;
  bf16x8 qfA0 = *(const bf16x8*)qpA;
  bf16x8 qfA1 = *(const bf16x8*)(qpA + 32);
  bf16x8 qfB0 = *(const bf16x8*)qpB;
  bf16x8 qfB1 = *(const bf16x8*)(qpB + 32);

  f32x4_t accOA[4] = {}, accOB[4] = {};
  float lA[4] = {}, lB[4] = {};                  // per-lane partial row sums
  const float SC = 0.125f * 1.44269504089f;

  // staging (r11): sp=t>>3 -> (kc,kh); dc=t&7; key pair (keyA, keyA+16)
  const int sp = t >> 3, dc = t & 7;
  const int kc = sp & 15, kh = sp >> 4;
  const int keyA = kc + 32 * kh;
  u16* ksA = Ks + keyA * SKS + dc * 8;
  u16* ksB = Ks + (keyA + 16) * SKS + dc * 8;
  const int vcol = kc * 4 + 2 * kh;
  const size_t kvbase = 1024 + head * 64 + dc * 8;

  const int nkv = (len + 63) >> 6;
  u32x4_t rkA, rkB, rvA, rvB;
  {   // prologue: tile 0
    int ta = start + (keyA      < len ? keyA      : len - 1);
    int tb = start + (keyA + 16 < len ? keyA + 16 : len - 1);
    const u16* pa = qkv + (size_t)ta * 3072 + kvbase;
    const u16* pb2 = qkv + (size_t)tb * 3072 + kvbase;
    rkA = *(const u32x4*)pa;   rvA = *(const u32x4*)(pa + 1024);
    rkB = *(const u32x4*)pb2;  rvB = *(const u32x4*)(pb2 + 1024);
  }

  for (int it = 0; it < nkv; ++it) {
    const int k0 = it << 6;
    __syncthreads();
    *(u32x4*)ksA = rkA;
    *(u32x4*)ksB = rkB;
    {
      const u16* a = (const u16*)&rvA;
      const u16* b = (const u16*)&rvB;
#pragma unroll
      for (int j = 0; j < 8; ++j) {
        u32 pk = (u32)a[j] | ((u32)b[j] << 16);
        *(u32*)(Vts + (dc * 8 + j) * SVS + vcol) = pk;
      }
    }
    __syncthreads();
    if (it + 1 < nkv) {                          // prefetch next tile
      int kb0 = k0 + 64;
      int ta = start + (kb0 + keyA      < len ? kb0 + keyA      : len - 1);
      int tb = start + (kb0 + keyA + 16 < len ? kb0 + keyA + 16 : len - 1);
      const u16* pa = qkv + (size_t)ta * 3072 + kvbase;
      const u16* pb2 = qkv + (size_t)tb * 3072 + kvbase;
      rkA = *(const u32x4*)pa;   rvA = *(const u32x4*)(pa + 1024);
      rkB = *(const u32x4*)pb2;  rvB = *(const u32x4*)(pb2 + 1024);
    }

    // S = Q.K^T for both row sets (independent chains)
    f32x4_t sgA[4], sgB[4];
#pragma unroll
    for (int g = 0; g < 4; ++g) {
      bf16x8 kb0 = *(const bf16x8*)(Ks + (g*16 + col) * SKS + quad * 8);
      bf16x8 kb1 = *(const bf16x8*)(Ks + (g*16 + col) * SKS + 32 + quad * 8);
      f32x4_t sA = {}, sB = {};
      sA = __builtin_amdgcn_mfma_f32_16x16x32_bf16(qfA0, kb0, sA, 0, 0, 0);
      sB = __builtin_amdgcn_mfma_f32_16x16x32_bf16(qfB0, kb0, sB, 0, 0, 0);
      sA = __builtin_amdgcn_mfma_f32_16x16x32_bf16(qfA1, kb1, sA, 0, 0, 0);
      sB = __builtin_amdgcn_mfma_f32_16x16x32_bf16(qfB1, kb1, sB, 0, 0, 0);
      sgA[g] = sA; sgB[g] = sB;
    }

    // P = exp2(S*SC), masked; key g*16+col -> column col*4+g (b64 rows)
    // L partials accumulate in-register from the SAME rounded bf16 values.
    const bool full = (k0 + 64 <= len);
    bool vg[4];
#pragma unroll
    for (int g = 0; g < 4; ++g) vg[g] = full || (k0 + g*16 + col) < len;
    u16* pwA = Ps + wave * (16 * SPS);
    u16* pwB = Ps + (4 + wave) * (16 * SPS);
#pragma unroll
    for (int r = 0; r < 4; ++r) {
      u16 peA[4], peB[4];
#pragma unroll
      for (int g = 0; g < 4; ++g) {
        float pA = exp2f(sgA[g][r] * SC);
        float pB = exp2f(sgB[g][r] * SC);
        peA[g] = vg[g] ? f2b(pA) : (u16)0;
        peB[g] = vg[g] ? f2b(pB) : (u16)0;
      }
      lA[r] += (b2f(peA[0]) + b2f(peA[1])) + (b2f(peA[2]) + b2f(peA[3]));
      lB[r] += (b2f(peB[0]) + b2f(peB[1])) + (b2f(peB[2]) + b2f(peB[3]));
      u32x2_t wA, wB;
      wA[0] = (u32)peA[0] | ((u32)peA[1] << 16);
      wA[1] = (u32)peA[2] | ((u32)peA[3] << 16);
      wB[0] = (u32)peB[0] | ((u32)peB[1] << 16);
      wB[1] = (u32)peB[2] | ((u32)peB[3] << 16);
      *(u32x2*)(pwA + (quad*4 + r) * SPS + col * 4) = wA;
      *(u32x2*)(pwB + (quad*4 + r) * SPS + col * 4) = wB;
    }
    __threadfence_block();

    bf16x8 pfA0 = *(const bf16x8*)(pwA + col * SPS + quad * 8);
    bf16x8 pfA1 = *(const bf16x8*)(pwA + col * SPS + 32 + quad * 8);
    bf16x8 pfB0 = *(const bf16x8*)(pwB + col * SPS + quad * 8);
    bf16x8 pfB1 = *(const bf16x8*)(pwB + col * SPS + 32 + quad * 8);
#pragma unroll
    for (int c = 0; c < 4; ++c) {
      bf16x8 vf0 = *(const bf16x8*)(Vts + (c*16 + col) * SVS + quad * 8);
      bf16x8 vf1 = *(const bf16x8*)(Vts + (c*16 + col) * SVS + 32 + quad * 8);
      accOA[c] = __builtin_amdgcn_mfma_f32_16x16x32_bf16(pfA0, vf0, accOA[c], 0, 0, 0);
      accOB[c] = __builtin_amdgcn_mfma_f32_16x16x32_bf16(pfB0, vf0, accOB[c], 0, 0, 0);
      accOA[c] = __builtin_amdgcn_mfma_f32_16x16x32_bf16(pfA1, vf1, accOA[c], 0, 0, 0);
      accOB[c] = __builtin_amdgcn_mfma_f32_16x16x32_bf16(pfB1, vf1, accOB[c], 0, 0, 0);
    }
  }

  // epilogue: finish L reduction across the 16 lanes sharing a quad
#pragma unroll
  for (int r = 0; r < 4; ++r) {
    float sA = lA[r], sB = lB[r];
    sA += __shfl_xor(sA, 1); sB += __shfl_xor(sB, 1);
    sA += __shfl_xor(sA, 2); sB += __shfl_xor(sB, 2);
    sA += __shfl_xor(sA, 4); sB += __shfl_xor(sB, 4);
    sA += __shfl_xor(sA, 8); sB += __shfl_xor(sB, 8);
    int rowA = q0 + wave * 16 + quad * 4 + r;
    int rowB = rowA + 64;
    if (rowA < len) {
      float inv = 1.0f / sA;
      u16* op = out + (size_t)(start + rowA) * 1024 + head * 64 + col;
      op[0]  = f2b(accOA[0][r] * inv);
      op[16] = f2b(accOA[1][r] * inv);
      op[32] = f2b(accOA[2][r] * inv);
      op[48] = f2b(accOA[3][r] * inv);
    }
    if (rowB < len) {
      float inv = 1.0f / sB;
      u16* op = out + (size_t)(start + rowB) * 1024 + head * 64 + col;
      op[0]  = f2b(accOB[0][r] * inv);
      op[16] = f2b(accOB[1][r] * inv);
      op[32] = f2b(accOB[2][r] * inv);
      op[48] = f2b(accOB[3][r] * inv);
    }
  }
}

__global__ void ws_too_small_sentinel(float* out) {
  if (threadIdx.x == 0 && blockIdx.x == 0) out[0] = 1024.0f;
}

// ---------------------------------------------------------------------------
extern "C" void kernel_launch(void* const* d_in, const int* in_sizes, int n_in,
                              void* d_out, int out_size, void* d_ws, size_t ws_size,
                              hipStream_t stream) {
  const float* x  = (const float*)d_in[0];
  const int*   cu = (const int*)d_in[1];
  const float* Wq = (const float*)d_in[2];
  const float* bq = (const float*)d_in[3];
  const float* Wk = (const float*)d_in[4];
  const float* bk = (const float*)d_in[5];
  const float* Wv = (const float*)d_in[6];
  const float* bv = (const float*)d_in[7];
  const float* qn = (const float*)d_in[8];
  const float* kn = (const float*)d_in[9];
  const float* Wo = (const float*)d_in[10];
  const float* bo = (const float*)d_in[11];

  const int T = in_sizes[0] / 1024;
  const int nseq = in_sizes[1] - 1;

  const size_t need_fast = ((size_t)T * 5120 + 4 * WSZ) * 2;   // 92.3 MB @ T=8192
  const size_t need_fall = (size_t)T * 4096 * 2;               // 67.1 MB

  u16* qkv  = (u16*)d_ws;
  u16* attn = qkv + (size_t)T * 3072;
  dim3 blk(256);

  if (ws_size >= need_fast) {
    u16* xb   = attn + (size_t)T * 1024;
    u16* wqkv = xb + (size_t)T * 1024;
    u16* wo   = wqkv + 3 * WSZ;
    cvt_pack<<<dim3(1024), blk, 0, stream>>>(x, Wq, Wk, Wv, Wo, xb, T * 1024);
    gemm8<1, 0><<<dim3((T + 255) / 256, 12), dim3(512), 0, stream>>>(
        xb, wqkv, bq, bk, bv, qn, kn, qkv, T, 1024, 3072);
    attn_fwd<<<dim3(16, 8, nseq), blk, 0, stream>>>(qkv, cu, attn);
    gemm_bt2<0, 1><<<dim3((T + 127) / 128, 8), blk, 0, stream>>>(
        attn, wo, bo, bo, bo, qn, kn, d_out, T, 1024, 1024);
  } else if (ws_size >= need_fall) {
    gemm_bt<1, 0><<<dim3((T + 127) / 128, 24), blk, 0, stream>>>(
        x, Wq, Wk, Wv, bq, bk, bv, qkv, T, 1024, 3072);
    rmsnorm_qk<<<dim3((2 * T * 256 + 255) / 256), blk, 0, stream>>>(qkv, qn, kn, T);
    attn_fwd<<<dim3(16, 8, nseq), blk, 0, stream>>>(qkv, cu, attn);
    gemm_bt<0, 1><<<dim3((T + 127) / 128, 8), blk, 0, stream>>>(
        attn, Wo, Wo, Wo, bo, bo, bo, d_out, T, 1024, 1024);
  } else {
    ws_too_small_sentinel<<<1, 64, 0, stream>>>((float*)d_out);
  }
}

// Round 16
// 265.970 us; speedup vs baseline: 1.0840x; 1.0201x over previous
//
#include <hip/hip_runtime.h>

typedef unsigned short u16;
typedef unsigned int   u32;

typedef __bf16 bf16x8_t __attribute__((ext_vector_type(8)));
typedef bf16x8_t bf16x8 __attribute__((may_alias));
typedef float f32x4_t __attribute__((ext_vector_type(4)));
typedef f32x4_t f32x4 __attribute__((may_alias));
typedef u32 u32x4_t __attribute__((ext_vector_type(4)));
typedef u32x4_t u32x4 __attribute__((may_alias));
typedef u32 u32x2_t __attribute__((ext_vector_type(2)));
typedef u32x2_t u32x2 __attribute__((may_alias));

__device__ __forceinline__ u16 f2b(float f) {        // RNE via hw cvt
  __bf16 h = (__bf16)f; u16 u; __builtin_memcpy(&u, &h, 2); return u;
}
__device__ __forceinline__ float b2f(u16 u) {
  u32 i = ((u32)u) << 16; float f; __builtin_memcpy(&f, &i, 4); return f;
}
__device__ __forceinline__ bf16x8_t cvt8(const float* p) {
  f32x4_t a = *(const f32x4*)p;
  f32x4_t b = *(const f32x4*)(p + 4);
  bf16x8_t v;
  v[0]=(__bf16)a[0]; v[1]=(__bf16)a[1]; v[2]=(__bf16)a[2]; v[3]=(__bf16)a[3];
  v[4]=(__bf16)b[0]; v[5]=(__bf16)b[1]; v[6]=(__bf16)b[2]; v[7]=(__bf16)b[3];
  return v;
}
// async global->LDS, 16B/lane (proper addrspacecast)
typedef __attribute__((address_space(1))) const void* as1cv;
typedef __attribute__((address_space(3))) void* as3v;
__device__ __forceinline__ void gld16(const u16* g, u16* l) {
  __builtin_amdgcn_global_load_lds((as1cv)g, (as3v)l, 16, 0, 0);
}

#define EPS 1.1920929e-07f

// ---------------------------------------------------------------------------
// cvt_pack: x (nx f32) + Wq|Wk|Wv|Wo (1M f32 each) -> bf16 blob (r10)
// ---------------------------------------------------------------------------
#define WSZ (1024 * 1024)
__global__ __launch_bounds__(256) void cvt_pack(
    const float* __restrict__ x, const float* __restrict__ wq,
    const float* __restrict__ wk, const float* __restrict__ wv,
    const float* __restrict__ wo, u16* __restrict__ dst, int nx)
{
  int idx4 = blockIdx.x * 256 + threadIdx.x;
  const int total4 = (nx + 4 * WSZ) >> 2;
  for (; idx4 < total4; idx4 += gridDim.x * 256) {
    int i = idx4 << 2;
    const float* src;
    if (i < nx) src = x + i;
    else {
      int o = i - nx;
      if      (o <     WSZ) src = wq + o;
      else if (o < 2 * WSZ) src = wk + o - WSZ;
      else if (o < 3 * WSZ) src = wv + o - 2 * WSZ;
      else                  src = wo + o - 3 * WSZ;
    }
    f32x4_t v = *(const f32x4*)src;
    u32x2_t p;
    p[0] = (u32)f2b(v[0]) | ((u32)f2b(v[1]) << 16);
    p[1] = (u32)f2b(v[2]) | ((u32)f2b(v[3]) << 16);
    *(u32x2*)(dst + i) = p;
  }
}

// ---------------------------------------------------------------------------
// gemm_bt2 (r10): m97 structure + fused RMSNorm epilogue. QKV duty restored
// per r11 pre-commitment (gemm8 v1/v2/v3 all measured slower; lane closed).
// ---------------------------------------------------------------------------
#define BK 32
template<int NORM, int CF32>
__global__ __launch_bounds__(256, 2) void gemm_bt2(
    const u16* __restrict__ A, const u16* __restrict__ Bm,
    const float* __restrict__ bias0, const float* __restrict__ bias1, const float* __restrict__ bias2,
    const float* __restrict__ qn, const float* __restrict__ kn,
    void* __restrict__ C, int M, int K, int ldc)
{
  __shared__ alignas(16) u16 As[128 * BK];
  __shared__ alignas(16) u16 Bs[128 * BK];
  const int t = threadIdx.x;
  const int lane = t & 63, wave = t >> 6;
  const int quad = lane >> 4, col = lane & 15;
  const int m0 = blockIdx.x * 128, n0 = blockIdx.y * 128;
  const int seg = n0 >> 10, nl0 = n0 & 1023;
  const float* bias = seg == 0 ? bias0 : (seg == 1 ? bias1 : bias2);
  const int wm = (wave >> 1) * 64, wn = (wave & 1) * 64;

  const int lrow = t >> 2;
  const int lcol = (t & 3) * 8;
  const u16* ga0 = A  + (size_t)(m0 + lrow) * K + lcol;
  const u16* ga1 = A  + (size_t)(m0 + 64 + lrow) * K + lcol;
  const u16* gb0 = Bm + (size_t)(n0 + lrow) * K + lcol;
  const u16* gb1 = Bm + (size_t)(n0 + 64 + lrow) * K + lcol;
  u16* lA0 = As + t * 8;
  u16* lA1 = As + 64 * BK + t * 8;
  u16* lB0 = Bs + t * 8;
  u16* lB1 = Bs + 64 * BK + t * 8;

  f32x4_t acc[4][4] = {};
  for (int k0 = 0; k0 < K; k0 += BK) {
    __syncthreads();
    gld16(ga0 + k0, lA0);
    gld16(ga1 + k0, lA1);
    gld16(gb0 + k0, lB0);
    gld16(gb1 + k0, lB1);
    __syncthreads();
    bf16x8 af[4], bfr[4];
#pragma unroll
    for (int i = 0; i < 4; ++i) {
      af[i]  = *(const bf16x8*)(As + (wm + i * 16 + col) * BK + quad * 8);
      bfr[i] = *(const bf16x8*)(Bs + (wn + i * 16 + col) * BK + quad * 8);
    }
#pragma unroll
    for (int i = 0; i < 4; ++i)
#pragma unroll
      for (int j = 0; j < 4; ++j)
        acc[i][j] = __builtin_amdgcn_mfma_f32_16x16x32_bf16(af[i], bfr[j], acc[i][j], 0, 0, 0);
  }

  float bz[4], wz[4];
#pragma unroll
  for (int j = 0; j < 4; ++j) {
    bz[j] = bias[nl0 + wn + j * 16 + col];
    if (NORM) wz[j] = (seg == 0 ? qn : kn)[j * 16 + col];
  }
  const bool donorm = NORM && seg < 2;
#pragma unroll
  for (int i = 0; i < 4; ++i) {
#pragma unroll
    for (int rr = 0; rr < 4; ++rr) {
      int gm = m0 + wm + i * 16 + quad * 4 + rr;
      float v[4];
#pragma unroll
      for (int j = 0; j < 4; ++j) v[j] = acc[i][j][rr] + bz[j];
      if (donorm) {
        float ss = v[0]*v[0] + v[1]*v[1] + v[2]*v[2] + v[3]*v[3];
        ss += __shfl_xor(ss, 1);
        ss += __shfl_xor(ss, 2);
        ss += __shfl_xor(ss, 4);
        ss += __shfl_xor(ss, 8);
        float sc = rsqrtf(ss * (1.0f / 64.0f) + EPS);
#pragma unroll
        for (int j = 0; j < 4; ++j) v[j] *= sc * wz[j];
      }
      if (gm < M) {
#pragma unroll
        for (int j = 0; j < 4; ++j) {
          int gn = n0 + wn + j * 16 + col;
          if (CF32) ((float*)C)[(size_t)gm * ldc + gn] = v[j];
          else      ((u16*)C)[(size_t)gm * ldc + gn] = f2b(v[j]);
        }
      }
    }
  }
}

// ---------------------------------------------------------------------------
// FALLBACK tier kernels (r9, unchanged)
// ---------------------------------------------------------------------------
template<int AF32, int CF32>
__global__ __launch_bounds__(256, 2) void gemm_bt(
    const void* __restrict__ Av,
    const float* __restrict__ B0, const float* __restrict__ B1, const float* __restrict__ B2,
    const float* __restrict__ bias0, const float* __restrict__ bias1, const float* __restrict__ bias2,
    void* __restrict__ C, int M, int K, int ldc)
{
  __shared__ alignas(16) u16 As[128 * BK];
  __shared__ alignas(16) u16 Bs[128 * BK];
  const int t = threadIdx.x;
  const int lane = t & 63, wave = t >> 6;
  const int quad = lane >> 4, col = lane & 15;
  const int m0 = blockIdx.x * 128, n0 = blockIdx.y * 128;
  const int seg = n0 >> 10;
  const float* B    = seg == 0 ? B0    : (seg == 1 ? B1    : B2);
  const float* bias = seg == 0 ? bias0 : (seg == 1 ? bias1 : bias2);
  const int nl0 = n0 & 1023;
  const int wm = (wave >> 1) * 64, wn = (wave & 1) * 64;
  const int lrow = t >> 2;
  const int lcol = (t & 3) * 8;
  int ar0 = m0 + lrow;      if (ar0 >= M) ar0 = M - 1;
  int ar1 = m0 + 64 + lrow; if (ar1 >= M) ar1 = M - 1;
  const float* bp0 = B + (size_t)(nl0 + lrow) * K + lcol;
  const float* bp1 = B + (size_t)(nl0 + 64 + lrow) * K + lcol;
  const float* apf0 = (const float*)Av + (size_t)ar0 * K + lcol;
  const float* apf1 = (const float*)Av + (size_t)ar1 * K + lcol;
  const u16*   aph0 = (const u16*)Av   + (size_t)ar0 * K + lcol;
  const u16*   aph1 = (const u16*)Av   + (size_t)ar1 * K + lcol;
  u16* lA0 = As + t * 8;
  u16* lA1 = As + 64 * BK + t * 8;
  u16* lB0 = Bs + t * 8;
  u16* lB1 = Bs + 64 * BK + t * 8;

  f32x4_t acc[4][4] = {};
  for (int k0 = 0; k0 < K; k0 += BK) {
    bf16x8_t va0, va1, vb0, vb1;
    if (AF32) { va0 = cvt8(apf0 + k0); va1 = cvt8(apf1 + k0); }
    else {
      u32x4_t r0 = *(const u32x4*)(aph0 + k0);
      u32x4_t r1 = *(const u32x4*)(aph1 + k0);
      __builtin_memcpy(&va0, &r0, 16);
      __builtin_memcpy(&va1, &r1, 16);
    }
    vb0 = cvt8(bp0 + k0);
    vb1 = cvt8(bp1 + k0);
    __syncthreads();
    *(bf16x8*)lA0 = va0; *(bf16x8*)lA1 = va1;
    *(bf16x8*)lB0 = vb0; *(bf16x8*)lB1 = vb1;
    __syncthreads();
    bf16x8 af[4], bfr[4];
#pragma unroll
    for (int i = 0; i < 4; ++i) {
      af[i]  = *(const bf16x8*)(As + (wm + i * 16 + col) * BK + quad * 8);
      bfr[i] = *(const bf16x8*)(Bs + (wn + i * 16 + col) * BK + quad * 8);
    }
#pragma unroll
    for (int i = 0; i < 4; ++i)
#pragma unroll
      for (int j = 0; j < 4; ++j)
        acc[i][j] = __builtin_amdgcn_mfma_f32_16x16x32_bf16(af[i], bfr[j], acc[i][j], 0, 0, 0);
  }
#pragma unroll
  for (int j = 0; j < 4; ++j) {
    int gn = n0 + wn + j * 16 + col;
    float bz = bias[nl0 + wn + j * 16 + col];
#pragma unroll
    for (int i = 0; i < 4; ++i) {
#pragma unroll
      for (int rr = 0; rr < 4; ++rr) {
        int gm = m0 + wm + i * 16 + quad * 4 + rr;
        if (gm < M) {
          float v = acc[i][j][rr] + bz;
          if (CF32) ((float*)C)[(size_t)gm * ldc + gn] = v;
          else      ((u16*)C)[(size_t)gm * ldc + gn] = f2b(v);
        }
      }
    }
  }
}

__global__ __launch_bounds__(256) void rmsnorm_qk(
    u16* __restrict__ qkv, const float* __restrict__ qn, const float* __restrict__ kn, int T)
{
  int gid = blockIdx.x * 256 + threadIdx.x;
  int row = gid >> 4, sub = gid & 15;
  if (row >= 2 * T * 16) return;
  int which = row >= T * 16;
  int r = which ? row - T * 16 : row;
  int tok = r >> 4, head = r & 15;
  u16* p = qkv + (size_t)tok * 3072 + which * 1024 + head * 64 + sub * 4;
  u16 d0 = p[0], d1 = p[1], d2 = p[2], d3 = p[3];
  float f0 = b2f(d0), f1 = b2f(d1), f2v = b2f(d2), f3 = b2f(d3);
  float ss = f0 * f0 + f1 * f1 + f2v * f2v + f3 * f3;
  ss += __shfl_xor(ss, 1);
  ss += __shfl_xor(ss, 2);
  ss += __shfl_xor(ss, 4);
  ss += __shfl_xor(ss, 8);
  float sc = rsqrtf(ss * (1.0f / 64.0f) + EPS);
  const float* w = which ? kn : qn;
  p[0] = f2b(f0 * sc * w[sub * 4 + 0]);
  p[1] = f2b(f1 * sc * w[sub * 4 + 1]);
  p[2] = f2b(f2v * sc * w[sub * 4 + 2]);
  p[3] = f2b(f3 * sc * w[sub * 4 + 3]);
}

// ---------------------------------------------------------------------------
// Flash attention v7 (4th submit; r12-r14 benches timed out): v6 (head-major
// grid, r4-verified) + T5 setprio around the two MFMA clusters (m191: +4-7%
// attn in this multi-independent-blocks-per-CU regime; pure hint).
// ---------------------------------------------------------------------------
#define SKS 68
#define SVS 68
#define SPS 68
__global__ __launch_bounds__(256, 4) void attn_fwd(
    const u16* __restrict__ qkv, const int* __restrict__ cu, u16* __restrict__ out)
{
  __shared__ alignas(16) u16 Ks[64 * SKS];
  __shared__ alignas(16) u16 Vts[64 * SVS];
  __shared__ alignas(16) u16 Ps[8 * 16 * SPS];   // 4 waves x 2 row-sets
  const int seq = blockIdx.z, head = blockIdx.x, qt = blockIdx.y;
  const int start = cu[seq], len = cu[seq + 1] - start;
  const int q0 = qt * 128;
  if (q0 >= len) return;
  const int t = threadIdx.x;
  const int lane = t & 63, wave = t >> 6, quad = lane >> 4, col = lane & 15;

  const int rA = q0 + wave * 16 + col, rB = rA + 64;
  const u16* qpA = qkv + (size_t)(start + (rA < len ? rA : len - 1)) * 3072 + head * 64 + quad * 8;
  const u16* qpB = qkv + (size_t)(start + (rB < len ? rB : len - 1)) * 3072 + head * 64 + quad * 8;
  bf16x8 qfA0 = *(const bf16x8*)qpA;
  bf16x8 qfA1 = *(const bf16x8*)(qpA + 32);
  bf16x8 qfB0 = *(const bf16x8*)qpB;
  bf16x8 qfB1 = *(const bf16x8*)(qpB + 32);

  f32x4_t accOA[4] = {}, accOB[4] = {};
  float lA[4] = {}, lB[4] = {};                  // per-lane partial row sums
  const float SC = 0.125f * 1.44269504089f;

  // staging (r11): sp=t>>3 -> (kc,kh); dc=t&7; key pair (keyA, keyA+16)
  const int sp = t >> 3, dc = t & 7;
  const int kc = sp & 15, kh = sp >> 4;
  const int keyA = kc + 32 * kh;
  u16* ksA = Ks + keyA * SKS + dc * 8;
  u16* ksB = Ks + (keyA + 16) * SKS + dc * 8;
  const int vcol = kc * 4 + 2 * kh;
  const size_t kvbase = 1024 + head * 64 + dc * 8;

  const int nkv = (len + 63) >> 6;
  u32x4_t rkA, rkB, rvA, rvB;
  {   // prologue: tile 0
    int ta = start + (keyA      < len ? keyA      : len - 1);
    int tb = start + (keyA + 16 < len ? keyA + 16 : len - 1);
    const u16* pa = qkv + (size_t)ta * 3072 + kvbase;
    const u16* pb2 = qkv + (size_t)tb * 3072 + kvbase;
    rkA = *(const u32x4*)pa;   rvA = *(const u32x4*)(pa + 1024);
    rkB = *(const u32x4*)pb2;  rvB = *(const u32x4*)(pb2 + 1024);
  }

  for (int it = 0; it < nkv; ++it) {
    const int k0 = it << 6;
    __syncthreads();
    *(u32x4*)ksA = rkA;
    *(u32x4*)ksB = rkB;
    {
      const u16* a = (const u16*)&rvA;
      const u16* b = (const u16*)&rvB;
#pragma unroll
      for (int j = 0; j < 8; ++j) {
        u32 pk = (u32)a[j] | ((u32)b[j] << 16);
        *(u32*)(Vts + (dc * 8 + j) * SVS + vcol) = pk;
      }
    }
    __syncthreads();
    if (it + 1 < nkv) {                          // prefetch next tile
      int kb0 = k0 + 64;
      int ta = start + (kb0 + keyA      < len ? kb0 + keyA      : len - 1);
      int tb = start + (kb0 + keyA + 16 < len ? kb0 + keyA + 16 : len - 1);
      const u16* pa = qkv + (size_t)ta * 3072 + kvbase;
      const u16* pb2 = qkv + (size_t)tb * 3072 + kvbase;
      rkA = *(const u32x4*)pa;   rvA = *(const u32x4*)(pa + 1024);
      rkB = *(const u32x4*)pb2;  rvB = *(const u32x4*)(pb2 + 1024);
    }

    // S = Q.K^T for both row sets (independent chains), setprio'd (T5)
    f32x4_t sgA[4], sgB[4];
    __builtin_amdgcn_s_setprio(1);
#pragma unroll
    for (int g = 0; g < 4; ++g) {
      bf16x8 kb0 = *(const bf16x8*)(Ks + (g*16 + col) * SKS + quad * 8);
      bf16x8 kb1 = *(const bf16x8*)(Ks + (g*16 + col) * SKS + 32 + quad * 8);
      f32x4_t sA = {}, sB = {};
      sA = __builtin_amdgcn_mfma_f32_16x16x32_bf16(qfA0, kb0, sA, 0, 0, 0);
      sB = __builtin_amdgcn_mfma_f32_16x16x32_bf16(qfB0, kb0, sB, 0, 0, 0);
      sA = __builtin_amdgcn_mfma_f32_16x16x32_bf16(qfA1, kb1, sA, 0, 0, 0);
      sB = __builtin_amdgcn_mfma_f32_16x16x32_bf16(qfB1, kb1, sB, 0, 0, 0);
      sgA[g] = sA; sgB[g] = sB;
    }
    __builtin_amdgcn_s_setprio(0);

    // P = exp2(S*SC), masked; key g*16+col -> column col*4+g (b64 rows)
    // L partials accumulate in-register from the SAME rounded bf16 values.
    const bool full = (k0 + 64 <= len);
    bool vg[4];
#pragma unroll
    for (int g = 0; g < 4; ++g) vg[g] = full || (k0 + g*16 + col) < len;
    u16* pwA = Ps + wave * (16 * SPS);
    u16* pwB = Ps + (4 + wave) * (16 * SPS);
#pragma unroll
    for (int r = 0; r < 4; ++r) {
      u16 peA[4], peB[4];
#pragma unroll
      for (int g = 0; g < 4; ++g) {
        float pA = exp2f(sgA[g][r] * SC);
        float pB = exp2f(sgB[g][r] * SC);
        peA[g] = vg[g] ? f2b(pA) : (u16)0;
        peB[g] = vg[g] ? f2b(pB) : (u16)0;
      }
      lA[r] += (b2f(peA[0]) + b2f(peA[1])) + (b2f(peA[2]) + b2f(peA[3]));
      lB[r] += (b2f(peB[0]) + b2f(peB[1])) + (b2f(peB[2]) + b2f(peB[3]));
      u32x2_t wA, wB;
      wA[0] = (u32)peA[0] | ((u32)peA[1] << 16);
      wA[1] = (u32)peA[2] | ((u32)peA[3] << 16);
      wB[0] = (u32)peB[0] | ((u32)peB[1] << 16);
      wB[1] = (u32)peB[2] | ((u32)peB[3] << 16);
      *(u32x2*)(pwA + (quad*4 + r) * SPS + col * 4) = wA;
      *(u32x2*)(pwB + (quad*4 + r) * SPS + col * 4) = wB;
    }
    __threadfence_block();

    bf16x8 pfA0 = *(const bf16x8*)(pwA + col * SPS + quad * 8);
    bf16x8 pfA1 = *(const bf16x8*)(pwA + col * SPS + 32 + quad * 8);
    bf16x8 pfB0 = *(const bf16x8*)(pwB + col * SPS + quad * 8);
    bf16x8 pfB1 = *(const bf16x8*)(pwB + col * SPS + 32 + quad * 8);
    __builtin_amdgcn_s_setprio(1);
#pragma unroll
    for (int c = 0; c < 4; ++c) {
      bf16x8 vf0 = *(const bf16x8*)(Vts + (c*16 + col) * SVS + quad * 8);
      bf16x8 vf1 = *(const bf16x8*)(Vts + (c*16 + col) * SVS + 32 + quad * 8);
      accOA[c] = __builtin_amdgcn_mfma_f32_16x16x32_bf16(pfA0, vf0, accOA[c], 0, 0, 0);
      accOB[c] = __builtin_amdgcn_mfma_f32_16x16x32_bf16(pfB0, vf0, accOB[c], 0, 0, 0);
      accOA[c] = __builtin_amdgcn_mfma_f32_16x16x32_bf16(pfA1, vf1, accOA[c], 0, 0, 0);
      accOB[c] = __builtin_amdgcn_mfma_f32_16x16x32_bf16(pfB1, vf1, accOB[c], 0, 0, 0);
    }
    __builtin_amdgcn_s_setprio(0);
  }

  // epilogue: finish L reduction across the 16 lanes sharing a quad
#pragma unroll
  for (int r = 0; r < 4; ++r) {
    float sA = lA[r], sB = lB[r];
    sA += __shfl_xor(sA, 1); sB += __shfl_xor(sB, 1);
    sA += __shfl_xor(sA, 2); sB += __shfl_xor(sB, 2);
    sA += __shfl_xor(sA, 4); sB += __shfl_xor(sB, 4);
    sA += __shfl_xor(sA, 8); sB += __shfl_xor(sB, 8);
    int rowA = q0 + wave * 16 + quad * 4 + r;
    int rowB = rowA + 64;
    if (rowA < len) {
      float inv = 1.0f / sA;
      u16* op = out + (size_t)(start + rowA) * 1024 + head * 64 + col;
      op[0]  = f2b(accOA[0][r] * inv);
      op[16] = f2b(accOA[1][r] * inv);
      op[32] = f2b(accOA[2][r] * inv);
      op[48] = f2b(accOA[3][r] * inv);
    }
    if (rowB < len) {
      float inv = 1.0f / sB;
      u16* op = out + (size_t)(start + rowB) * 1024 + head * 64 + col;
      op[0]  = f2b(accOB[0][r] * inv);
      op[16] = f2b(accOB[1][r] * inv);
      op[32] = f2b(accOB[2][r] * inv);
      op[48] = f2b(accOB[3][r] * inv);
    }
  }
}

__global__ void ws_too_small_sentinel(float* out) {
  if (threadIdx.x == 0 && blockIdx.x == 0) out[0] = 1024.0f;
}

// ---------------------------------------------------------------------------
extern "C" void kernel_launch(void* const* d_in, const int* in_sizes, int n_in,
                              void* d_out, int out_size, void* d_ws, size_t ws_size,
                              hipStream_t stream) {
  const float* x  = (const float*)d_in[0];
  const int*   cu = (const int*)d_in[1];
  const float* Wq = (const float*)d_in[2];
  const float* bq = (const float*)d_in[3];
  const float* Wk = (const float*)d_in[4];
  const float* bk = (const float*)d_in[5];
  const float* Wv = (const float*)d_in[6];
  const float* bv = (const float*)d_in[7];
  const float* qn = (const float*)d_in[8];
  const float* kn = (const float*)d_in[9];
  const float* Wo = (const float*)d_in[10];
  const float* bo = (const float*)d_in[11];

  const int T = in_sizes[0] / 1024;
  const int nseq = in_sizes[1] - 1;

  const size_t need_fast = ((size_t)T * 5120 + 4 * WSZ) * 2;   // 92.3 MB @ T=8192
  const size_t need_fall = (size_t)T * 4096 * 2;               // 67.1 MB

  u16* qkv  = (u16*)d_ws;
  u16* attn = qkv + (size_t)T * 3072;
  dim3 blk(256);

  if (ws_size >= need_fast) {
    u16* xb   = attn + (size_t)T * 1024;
    u16* wqkv = xb + (size_t)T * 1024;
    u16* wo   = wqkv + 3 * WSZ;
    cvt_pack<<<dim3(1024), blk, 0, stream>>>(x, Wq, Wk, Wv, Wo, xb, T * 1024);
    gemm_bt2<1, 0><<<dim3((T + 127) / 128, 24), blk, 0, stream>>>(
        xb, wqkv, bq, bk, bv, qn, kn, qkv, T, 1024, 3072);
    attn_fwd<<<dim3(16, 8, nseq), blk, 0, stream>>>(qkv, cu, attn);
    gemm_bt2<0, 1><<<dim3((T + 127) / 128, 8), blk, 0, stream>>>(
        attn, wo, bo, bo, bo, qn, kn, d_out, T, 1024, 1024);
  } else if (ws_size >= need_fall) {
    gemm_bt<1, 0><<<dim3((T + 127) / 128, 24), blk, 0, stream>>>(
        x, Wq, Wk, Wv, bq, bk, bv, qkv, T, 1024, 3072);
    rmsnorm_qk<<<dim3((2 * T * 256 + 255) / 256), blk, 0, stream>>>(qkv, qn, kn, T);
    attn_fwd<<<dim3(16, 8, nseq), blk, 0, stream>>>(qkv, cu, attn);
    gemm_bt<0, 1><<<dim3((T + 127) / 128, 8), blk, 0, stream>>>(
        attn, Wo, Wo, Wo, bo, bo, bo, d_out, T, 1024, 1024);
  } else {
    ws_too_small_sentinel<<<1, 64, 0, stream>>>((float*)d_out);
  }
}

// Round 17
// 248.394 us; speedup vs baseline: 1.1607x; 1.0708x over previous
//
#include <hip/hip_runtime.h>

typedef unsigned short u16;
typedef unsigned int   u32;

typedef __bf16 bf16x8_t __attribute__((ext_vector_type(8)));
typedef bf16x8_t bf16x8 __attribute__((may_alias));
typedef float f32x4_t __attribute__((ext_vector_type(4)));
typedef f32x4_t f32x4 __attribute__((may_alias));
typedef u32 u32x4_t __attribute__((ext_vector_type(4)));
typedef u32x4_t u32x4 __attribute__((may_alias));
typedef u32 u32x2_t __attribute__((ext_vector_type(2)));
typedef u32x2_t u32x2 __attribute__((may_alias));

__device__ __forceinline__ u16 f2b(float f) {        // RNE via hw cvt
  __bf16 h = (__bf16)f; u16 u; __builtin_memcpy(&u, &h, 2); return u;
}
__device__ __forceinline__ float b2f(u16 u) {
  u32 i = ((u32)u) << 16; float f; __builtin_memcpy(&f, &i, 4); return f;
}
__device__ __forceinline__ bf16x8_t cvt8(const float* p) {
  f32x4_t a = *(const f32x4*)p;
  f32x4_t b = *(const f32x4*)(p + 4);
  bf16x8_t v;
  v[0]=(__bf16)a[0]; v[1]=(__bf16)a[1]; v[2]=(__bf16)a[2]; v[3]=(__bf16)a[3];
  v[4]=(__bf16)b[0]; v[5]=(__bf16)b[1]; v[6]=(__bf16)b[2]; v[7]=(__bf16)b[3];
  return v;
}
// async global->LDS, 16B/lane (proper addrspacecast)
typedef __attribute__((address_space(1))) const void* as1cv;
typedef __attribute__((address_space(3))) void* as3v;
__device__ __forceinline__ void gld16(const u16* g, u16* l) {
  __builtin_amdgcn_global_load_lds((as1cv)g, (as3v)l, 16, 0, 0);
}

#define EPS 1.1920929e-07f

// ---------------------------------------------------------------------------
// cvt_pack: x (nx f32) + Wq|Wk|Wv|Wo (1M f32 each) -> bf16 blob (r10)
// ---------------------------------------------------------------------------
#define WSZ (1024 * 1024)
__global__ __launch_bounds__(256) void cvt_pack(
    const float* __restrict__ x, const float* __restrict__ wq,
    const float* __restrict__ wk, const float* __restrict__ wv,
    const float* __restrict__ wo, u16* __restrict__ dst, int nx)
{
  int idx4 = blockIdx.x * 256 + threadIdx.x;
  const int total4 = (nx + 4 * WSZ) >> 2;
  for (; idx4 < total4; idx4 += gridDim.x * 256) {
    int i = idx4 << 2;
    const float* src;
    if (i < nx) src = x + i;
    else {
      int o = i - nx;
      if      (o <     WSZ) src = wq + o;
      else if (o < 2 * WSZ) src = wk + o - WSZ;
      else if (o < 3 * WSZ) src = wv + o - 2 * WSZ;
      else                  src = wo + o - 3 * WSZ;
    }
    f32x4_t v = *(const f32x4*)src;
    u32x2_t p;
    p[0] = (u32)f2b(v[0]) | ((u32)f2b(v[1]) << 16);
    p[1] = (u32)f2b(v[2]) | ((u32)f2b(v[3]) << 16);
    *(u32x2*)(dst + i) = p;
  }
}

// ---------------------------------------------------------------------------
// gemm_bt3 (r17): gemm_bt2's m97 structure + fused RMSNorm epilogue, with
// BK 32->64 and the gemm8-verified both-sides chunk swizzle.
//  * Mechanism 1: K-steps 32->16 at K=1024 -> per-step barrier drains halved
//    (m97 analysis: ~20% of time is the pre-barrier waitcnt drain).
//    BK=64 is 32KB LDS total -> no occupancy cliff (m132's regression was
//    BK=128 @ 64KB).
//  * Mechanism 2: r16 counters showed 6.3M SQ_LDS_BANK_CONFLICT = the BK=32
//    frag-read's 8-way conflict (bank = row*16+quad*4 with row*16%32 only
//    taking {0,16}). At BK=64 each 128x64 tile is EXACTLY gemm8's half-tile:
//    staging (srow=t>>3, chunk=t&7, source col ^(srow&7), linear gld16 dest)
//    and swizzled read (chunk (ks*4+quad)^(col&7)) copy verbatim from the
//    r5/r7 twice-refcheck'd gemm8 -> 2-way access = free (m136).
// Epilogue unchanged (per-wave 64-col head alignment preserved).
// ---------------------------------------------------------------------------
#define BK2 64
template<int NORM, int CF32>
__global__ __launch_bounds__(256, 2) void gemm_bt3(
    const u16* __restrict__ A, const u16* __restrict__ Bm,
    const float* __restrict__ bias0, const float* __restrict__ bias1, const float* __restrict__ bias2,
    const float* __restrict__ qn, const float* __restrict__ kn,
    void* __restrict__ C, int M, int K, int ldc)
{
  __shared__ alignas(16) u16 As[128 * BK2];   // 16 KB
  __shared__ alignas(16) u16 Bs[128 * BK2];   // 16 KB
  const int t = threadIdx.x;
  const int lane = t & 63, wave = t >> 6;
  const int quad = lane >> 4, col = lane & 15;
  const int m0 = blockIdx.x * 128, n0 = blockIdx.y * 128;
  const int seg = n0 >> 10, nl0 = n0 & 1023;
  const float* bias = seg == 0 ? bias0 : (seg == 1 ? bias1 : bias2);
  const int wm = (wave >> 1) * 64, wn = (wave & 1) * 64;

  // staging: thread t -> row slice q*32 + (t>>3), 16B chunk (t&7);
  // global source chunk pre-swizzled by ^(srow&7)  [srow&7 == row&7, q*32%8==0]
  const int srow = t >> 3;                       // 0..31
  const int sx = ((t & 7) ^ (srow & 7)) << 3;    // u16 offset in 64-elem row
  const u16* ga[4];
  const u16* gb[4];
#pragma unroll
  for (int q = 0; q < 4; ++q) {
    int ar = m0 + q * 32 + srow; if (ar >= M) ar = M - 1;
    ga[q] = A  + (size_t)ar * K + sx;
    gb[q] = Bm + (size_t)(n0 + q * 32 + srow) * K + sx;
  }
  const int dst8 = t * 8;                        // linear dest within 4KB slice

  f32x4_t acc[4][4] = {};
  for (int k0 = 0; k0 < K; k0 += BK2) {
    __syncthreads();
#pragma unroll
    for (int q = 0; q < 4; ++q) {
      gld16(ga[q] + k0, As + q * 2048 + dst8);
      gld16(gb[q] + k0, Bs + q * 2048 + dst8);
    }
    __syncthreads();
#pragma unroll
    for (int ks = 0; ks < 2; ++ks) {
      const int ck = (((ks * 4 + quad) ^ (col & 7)) << 3);
      bf16x8 af[4], bfr[4];
#pragma unroll
      for (int i = 0; i < 4; ++i) {
        af[i]  = *(const bf16x8*)(As + ((wm + i * 16 + col) << 6) + ck);
        bfr[i] = *(const bf16x8*)(Bs + ((wn + i * 16 + col) << 6) + ck);
      }
#pragma unroll
      for (int i = 0; i < 4; ++i)
#pragma unroll
        for (int j = 0; j < 4; ++j)
          acc[i][j] = __builtin_amdgcn_mfma_f32_16x16x32_bf16(af[i], bfr[j], acc[i][j], 0, 0, 0);
    }
  }

  float bz[4], wz[4];
#pragma unroll
  for (int j = 0; j < 4; ++j) {
    bz[j] = bias[nl0 + wn + j * 16 + col];
    if (NORM) wz[j] = (seg == 0 ? qn : kn)[j * 16 + col];
  }
  const bool donorm = NORM && seg < 2;
#pragma unroll
  for (int i = 0; i < 4; ++i) {
#pragma unroll
    for (int rr = 0; rr < 4; ++rr) {
      int gm = m0 + wm + i * 16 + quad * 4 + rr;
      float v[4];
#pragma unroll
      for (int j = 0; j < 4; ++j) v[j] = acc[i][j][rr] + bz[j];
      if (donorm) {
        float ss = v[0]*v[0] + v[1]*v[1] + v[2]*v[2] + v[3]*v[3];
        ss += __shfl_xor(ss, 1);
        ss += __shfl_xor(ss, 2);
        ss += __shfl_xor(ss, 4);
        ss += __shfl_xor(ss, 8);
        float sc = rsqrtf(ss * (1.0f / 64.0f) + EPS);
#pragma unroll
        for (int j = 0; j < 4; ++j) v[j] *= sc * wz[j];
      }
      if (gm < M) {
#pragma unroll
        for (int j = 0; j < 4; ++j) {
          int gn = n0 + wn + j * 16 + col;
          if (CF32) ((float*)C)[(size_t)gm * ldc + gn] = v[j];
          else      ((u16*)C)[(size_t)gm * ldc + gn] = f2b(v[j]);
        }
      }
    }
  }
}

// ---------------------------------------------------------------------------
// FALLBACK tier kernels (r9, unchanged)
// ---------------------------------------------------------------------------
#define BK 32
template<int AF32, int CF32>
__global__ __launch_bounds__(256, 2) void gemm_bt(
    const void* __restrict__ Av,
    const float* __restrict__ B0, const float* __restrict__ B1, const float* __restrict__ B2,
    const float* __restrict__ bias0, const float* __restrict__ bias1, const float* __restrict__ bias2,
    void* __restrict__ C, int M, int K, int ldc)
{
  __shared__ alignas(16) u16 As[128 * BK];
  __shared__ alignas(16) u16 Bs[128 * BK];
  const int t = threadIdx.x;
  const int lane = t & 63, wave = t >> 6;
  const int quad = lane >> 4, col = lane & 15;
  const int m0 = blockIdx.x * 128, n0 = blockIdx.y * 128;
  const int seg = n0 >> 10;
  const float* B    = seg == 0 ? B0    : (seg == 1 ? B1    : B2);
  const float* bias = seg == 0 ? bias0 : (seg == 1 ? bias1 : bias2);
  const int nl0 = n0 & 1023;
  const int wm = (wave >> 1) * 64, wn = (wave & 1) * 64;
  const int lrow = t >> 2;
  const int lcol = (t & 3) * 8;
  int ar0 = m0 + lrow;      if (ar0 >= M) ar0 = M - 1;
  int ar1 = m0 + 64 + lrow; if (ar1 >= M) ar1 = M - 1;
  const float* bp0 = B + (size_t)(nl0 + lrow) * K + lcol;
  const float* bp1 = B + (size_t)(nl0 + 64 + lrow) * K + lcol;
  const float* apf0 = (const float*)Av + (size_t)ar0 * K + lcol;
  const float* apf1 = (const float*)Av + (size_t)ar1 * K + lcol;
  const u16*   aph0 = (const u16*)Av   + (size_t)ar0 * K + lcol;
  const u16*   aph1 = (const u16*)Av   + (size_t)ar1 * K + lcol;
  u16* lA0 = As + t * 8;
  u16* lA1 = As + 64 * BK + t * 8;
  u16* lB0 = Bs + t * 8;
  u16* lB1 = Bs + 64 * BK + t * 8;

  f32x4_t acc[4][4] = {};
  for (int k0 = 0; k0 < K; k0 += BK) {
    bf16x8_t va0, va1, vb0, vb1;
    if (AF32) { va0 = cvt8(apf0 + k0); va1 = cvt8(apf1 + k0); }
    else {
      u32x4_t r0 = *(const u32x4*)(aph0 + k0);
      u32x4_t r1 = *(const u32x4*)(aph1 + k0);
      __builtin_memcpy(&va0, &r0, 16);
      __builtin_memcpy(&va1, &r1, 16);
    }
    vb0 = cvt8(bp0 + k0);
    vb1 = cvt8(bp1 + k0);
    __syncthreads();
    *(bf16x8*)lA0 = va0; *(bf16x8*)lA1 = va1;
    *(bf16x8*)lB0 = vb0; *(bf16x8*)lB1 = vb1;
    __syncthreads();
    bf16x8 af[4], bfr[4];
#pragma unroll
    for (int i = 0; i < 4; ++i) {
      af[i]  = *(const bf16x8*)(As + (wm + i * 16 + col) * BK + quad * 8);
      bfr[i] = *(const bf16x8*)(Bs + (wn + i * 16 + col) * BK + quad * 8);
    }
#pragma unroll
    for (int i = 0; i < 4; ++i)
#pragma unroll
      for (int j = 0; j < 4; ++j)
        acc[i][j] = __builtin_amdgcn_mfma_f32_16x16x32_bf16(af[i], bfr[j], acc[i][j], 0, 0, 0);
  }
#pragma unroll
  for (int j = 0; j < 4; ++j) {
    int gn = n0 + wn + j * 16 + col;
    float bz = bias[nl0 + wn + j * 16 + col];
#pragma unroll
    for (int i = 0; i < 4; ++i) {
#pragma unroll
      for (int rr = 0; rr < 4; ++rr) {
        int gm = m0 + wm + i * 16 + quad * 4 + rr;
        if (gm < M) {
          float v = acc[i][j][rr] + bz;
          if (CF32) ((float*)C)[(size_t)gm * ldc + gn] = v;
          else      ((u16*)C)[(size_t)gm * ldc + gn] = f2b(v);
        }
      }
    }
  }
}

__global__ __launch_bounds__(256) void rmsnorm_qk(
    u16* __restrict__ qkv, const float* __restrict__ qn, const float* __restrict__ kn, int T)
{
  int gid = blockIdx.x * 256 + threadIdx.x;
  int row = gid >> 4, sub = gid & 15;
  if (row >= 2 * T * 16) return;
  int which = row >= T * 16;
  int r = which ? row - T * 16 : row;
  int tok = r >> 4, head = r & 15;
  u16* p = qkv + (size_t)tok * 3072 + which * 1024 + head * 64 + sub * 4;
  u16 d0 = p[0], d1 = p[1], d2 = p[2], d3 = p[3];
  float f0 = b2f(d0), f1 = b2f(d1), f2v = b2f(d2), f3 = b2f(d3);
  float ss = f0 * f0 + f1 * f1 + f2v * f2v + f3 * f3;
  ss += __shfl_xor(ss, 1);
  ss += __shfl_xor(ss, 2);
  ss += __shfl_xor(ss, 4);
  ss += __shfl_xor(ss, 8);
  float sc = rsqrtf(ss * (1.0f / 64.0f) + EPS);
  const float* w = which ? kn : qn;
  p[0] = f2b(f0 * sc * w[sub * 4 + 0]);
  p[1] = f2b(f1 * sc * w[sub * 4 + 1]);
  p[2] = f2b(f2v * sc * w[sub * 4 + 2]);
  p[3] = f2b(f3 * sc * w[sub * 4 + 3]);
}

// ---------------------------------------------------------------------------
// Flash attention v7 (r16-measured, part of best config 265.97us): head-major
// grid + T5 setprio around MFMA clusters (~neutral-positive, kept).
// ---------------------------------------------------------------------------
#define SKS 68
#define SVS 68
#define SPS 68
__global__ __launch_bounds__(256, 4) void attn_fwd(
    const u16* __restrict__ qkv, const int* __restrict__ cu, u16* __restrict__ out)
{
  __shared__ alignas(16) u16 Ks[64 * SKS];
  __shared__ alignas(16) u16 Vts[64 * SVS];
  __shared__ alignas(16) u16 Ps[8 * 16 * SPS];   // 4 waves x 2 row-sets
  const int seq = blockIdx.z, head = blockIdx.x, qt = blockIdx.y;
  const int start = cu[seq], len = cu[seq + 1] - start;
  const int q0 = qt * 128;
  if (q0 >= len) return;
  const int t = threadIdx.x;
  const int lane = t & 63, wave = t >> 6, quad = lane >> 4, col = lane & 15;

  const int rA = q0 + wave * 16 + col, rB = rA + 64;
  const u16* qpA = qkv + (size_t)(start + (rA < len ? rA : len - 1)) * 3072 + head * 64 + quad * 8;
  const u16* qpB = qkv + (size_t)(start + (rB < len ? rB : len - 1)) * 3072 + head * 64 + quad * 8;
  bf16x8 qfA0 = *(const bf16x8*)qpA;
  bf16x8 qfA1 = *(const bf16x8*)(qpA + 32);
  bf16x8 qfB0 = *(const bf16x8*)qpB;
  bf16x8 qfB1 = *(const bf16x8*)(qpB + 32);

  f32x4_t accOA[4] = {}, accOB[4] = {};
  float lA[4] = {}, lB[4] = {};                  // per-lane partial row sums
  const float SC = 0.125f * 1.44269504089f;

  // staging (r11): sp=t>>3 -> (kc,kh); dc=t&7; key pair (keyA, keyA+16)
  const int sp = t >> 3, dc = t & 7;
  const int kc = sp & 15, kh = sp >> 4;
  const int keyA = kc + 32 * kh;
  u16* ksA = Ks + keyA * SKS + dc * 8;
  u16* ksB = Ks + (keyA + 16) * SKS + dc * 8;
  const int vcol = kc * 4 + 2 * kh;
  const size_t kvbase = 1024 + head * 64 + dc * 8;

  const int nkv = (len + 63) >> 6;
  u32x4_t rkA, rkB, rvA, rvB;
  {   // prologue: tile 0
    int ta = start + (keyA      < len ? keyA      : len - 1);
    int tb = start + (keyA + 16 < len ? keyA + 16 : len - 1);
    const u16* pa = qkv + (size_t)ta * 3072 + kvbase;
    const u16* pb2 = qkv + (size_t)tb * 3072 + kvbase;
    rkA = *(const u32x4*)pa;   rvA = *(const u32x4*)(pa + 1024);
    rkB = *(const u32x4*)pb2;  rvB = *(const u32x4*)(pb2 + 1024);
  }

  for (int it = 0; it < nkv; ++it) {
    const int k0 = it << 6;
    __syncthreads();
    *(u32x4*)ksA = rkA;
    *(u32x4*)ksB = rkB;
    {
      const u16* a = (const u16*)&rvA;
      const u16* b = (const u16*)&rvB;
#pragma unroll
      for (int j = 0; j < 8; ++j) {
        u32 pk = (u32)a[j] | ((u32)b[j] << 16);
        *(u32*)(Vts + (dc * 8 + j) * SVS + vcol) = pk;
      }
    }
    __syncthreads();
    if (it + 1 < nkv) {                          // prefetch next tile
      int kb0 = k0 + 64;
      int ta = start + (kb0 + keyA      < len ? kb0 + keyA      : len - 1);
      int tb = start + (kb0 + keyA + 16 < len ? kb0 + keyA + 16 : len - 1);
      const u16* pa = qkv + (size_t)ta * 3072 + kvbase;
      const u16* pb2 = qkv + (size_t)tb * 3072 + kvbase;
      rkA = *(const u32x4*)pa;   rvA = *(const u32x4*)(pa + 1024);
      rkB = *(const u32x4*)pb2;  rvB = *(const u32x4*)(pb2 + 1024);
    }

    // S = Q.K^T for both row sets (independent chains), setprio'd (T5)
    f32x4_t sgA[4], sgB[4];
    __builtin_amdgcn_s_setprio(1);
#pragma unroll
    for (int g = 0; g < 4; ++g) {
      bf16x8 kb0 = *(const bf16x8*)(Ks + (g*16 + col) * SKS + quad * 8);
      bf16x8 kb1 = *(const bf16x8*)(Ks + (g*16 + col) * SKS + 32 + quad * 8);
      f32x4_t sA = {}, sB = {};
      sA = __builtin_amdgcn_mfma_f32_16x16x32_bf16(qfA0, kb0, sA, 0, 0, 0);
      sB = __builtin_amdgcn_mfma_f32_16x16x32_bf16(qfB0, kb0, sB, 0, 0, 0);
      sA = __builtin_amdgcn_mfma_f32_16x16x32_bf16(qfA1, kb1, sA, 0, 0, 0);
      sB = __builtin_amdgcn_mfma_f32_16x16x32_bf16(qfB1, kb1, sB, 0, 0, 0);
      sgA[g] = sA; sgB[g] = sB;
    }
    __builtin_amdgcn_s_setprio(0);

    // P = exp2(S*SC), masked; key g*16+col -> column col*4+g (b64 rows)
    // L partials accumulate in-register from the SAME rounded bf16 values.
    const bool full = (k0 + 64 <= len);
    bool vg[4];
#pragma unroll
    for (int g = 0; g < 4; ++g) vg[g] = full || (k0 + g*16 + col) < len;
    u16* pwA = Ps + wave * (16 * SPS);
    u16* pwB = Ps + (4 + wave) * (16 * SPS);
#pragma unroll
    for (int r = 0; r < 4; ++r) {
      u16 peA[4], peB[4];
#pragma unroll
      for (int g = 0; g < 4; ++g) {
        float pA = exp2f(sgA[g][r] * SC);
        float pB = exp2f(sgB[g][r] * SC);
        peA[g] = vg[g] ? f2b(pA) : (u16)0;
        peB[g] = vg[g] ? f2b(pB) : (u16)0;
      }
      lA[r] += (b2f(peA[0]) + b2f(peA[1])) + (b2f(peA[2]) + b2f(peA[3]));
      lB[r] += (b2f(peB[0]) + b2f(peB[1])) + (b2f(peB[2]) + b2f(peB[3]));
      u32x2_t wA, wB;
      wA[0] = (u32)peA[0] | ((u32)peA[1] << 16);
      wA[1] = (u32)peA[2] | ((u32)peA[3] << 16);
      wB[0] = (u32)peB[0] | ((u32)peB[1] << 16);
      wB[1] = (u32)peB[2] | ((u32)peB[3] << 16);
      *(u32x2*)(pwA + (quad*4 + r) * SPS + col * 4) = wA;
      *(u32x2*)(pwB + (quad*4 + r) * SPS + col * 4) = wB;
    }
    __threadfence_block();

    bf16x8 pfA0 = *(const bf16x8*)(pwA + col * SPS + quad * 8);
    bf16x8 pfA1 = *(const bf16x8*)(pwA + col * SPS + 32 + quad * 8);
    bf16x8 pfB0 = *(const bf16x8*)(pwB + col * SPS + quad * 8);
    bf16x8 pfB1 = *(const bf16x8*)(pwB + col * SPS + 32 + quad * 8);
    __builtin_amdgcn_s_setprio(1);
#pragma unroll
    for (int c = 0; c < 4; ++c) {
      bf16x8 vf0 = *(const bf16x8*)(Vts + (c*16 + col) * SVS + quad * 8);
      bf16x8 vf1 = *(const bf16x8*)(Vts + (c*16 + col) * SVS + 32 + quad * 8);
      accOA[c] = __builtin_amdgcn_mfma_f32_16x16x32_bf16(pfA0, vf0, accOA[c], 0, 0, 0);
      accOB[c] = __builtin_amdgcn_mfma_f32_16x16x32_bf16(pfB0, vf0, accOB[c], 0, 0, 0);
      accOA[c] = __builtin_amdgcn_mfma_f32_16x16x32_bf16(pfA1, vf1, accOA[c], 0, 0, 0);
      accOB[c] = __builtin_amdgcn_mfma_f32_16x16x32_bf16(pfB1, vf1, accOB[c], 0, 0, 0);
    }
    __builtin_amdgcn_s_setprio(0);
  }

  // epilogue: finish L reduction across the 16 lanes sharing a quad
#pragma unroll
  for (int r = 0; r < 4; ++r) {
    float sA = lA[r], sB = lB[r];
    sA += __shfl_xor(sA, 1); sB += __shfl_xor(sB, 1);
    sA += __shfl_xor(sA, 2); sB += __shfl_xor(sB, 2);
    sA += __shfl_xor(sA, 4); sB += __shfl_xor(sB, 4);
    sA += __shfl_xor(sA, 8); sB += __shfl_xor(sB, 8);
    int rowA = q0 + wave * 16 + quad * 4 + r;
    int rowB = rowA + 64;
    if (rowA < len) {
      float inv = 1.0f / sA;
      u16* op = out + (size_t)(start + rowA) * 1024 + head * 64 + col;
      op[0]  = f2b(accOA[0][r] * inv);
      op[16] = f2b(accOA[1][r] * inv);
      op[32] = f2b(accOA[2][r] * inv);
      op[48] = f2b(accOA[3][r] * inv);
    }
    if (rowB < len) {
      float inv = 1.0f / sB;
      u16* op = out + (size_t)(start + rowB) * 1024 + head * 64 + col;
      op[0]  = f2b(accOB[0][r] * inv);
      op[16] = f2b(accOB[1][r] * inv);
      op[32] = f2b(accOB[2][r] * inv);
      op[48] = f2b(accOB[3][r] * inv);
    }
  }
}

__global__ void ws_too_small_sentinel(float* out) {
  if (threadIdx.x == 0 && blockIdx.x == 0) out[0] = 1024.0f;
}

// ---------------------------------------------------------------------------
extern "C" void kernel_launch(void* const* d_in, const int* in_sizes, int n_in,
                              void* d_out, int out_size, void* d_ws, size_t ws_size,
                              hipStream_t stream) {
  const float* x  = (const float*)d_in[0];
  const int*   cu = (const int*)d_in[1];
  const float* Wq = (const float*)d_in[2];
  const float* bq = (const float*)d_in[3];
  const float* Wk = (const float*)d_in[4];
  const float* bk = (const float*)d_in[5];
  const float* Wv = (const float*)d_in[6];
  const float* bv = (const float*)d_in[7];
  const float* qn = (const float*)d_in[8];
  const float* kn = (const float*)d_in[9];
  const float* Wo = (const float*)d_in[10];
  const float* bo = (const float*)d_in[11];

  const int T = in_sizes[0] / 1024;
  const int nseq = in_sizes[1] - 1;

  const size_t need_fast = ((size_t)T * 5120 + 4 * WSZ) * 2;   // 92.3 MB @ T=8192
  const size_t need_fall = (size_t)T * 4096 * 2;               // 67.1 MB

  u16* qkv  = (u16*)d_ws;
  u16* attn = qkv + (size_t)T * 3072;
  dim3 blk(256);

  if (ws_size >= need_fast) {
    u16* xb   = attn + (size_t)T * 1024;
    u16* wqkv = xb + (size_t)T * 1024;
    u16* wo   = wqkv + 3 * WSZ;
    cvt_pack<<<dim3(1024), blk, 0, stream>>>(x, Wq, Wk, Wv, Wo, xb, T * 1024);
    gemm_bt3<1, 0><<<dim3((T + 127) / 128, 24), blk, 0, stream>>>(
        xb, wqkv, bq, bk, bv, qn, kn, qkv, T, 1024, 3072);
    attn_fwd<<<dim3(16, 8, nseq), blk, 0, stream>>>(qkv, cu, attn);
    gemm_bt3<0, 1><<<dim3((T + 127) / 128, 8), blk, 0, stream>>>(
        attn, wo, bo, bo, bo, qn, kn, d_out, T, 1024, 1024);
  } else if (ws_size >= need_fall) {
    gemm_bt<1, 0><<<dim3((T + 127) / 128, 24), blk, 0, stream>>>(
        x, Wq, Wk, Wv, bq, bk, bv, qkv, T, 1024, 3072);
    rmsnorm_qk<<<dim3((2 * T * 256 + 255) / 256), blk, 0, stream>>>(qkv, qn, kn, T);
    attn_fwd<<<dim3(16, 8, nseq), blk, 0, stream>>>(qkv, cu, attn);
    gemm_bt<0, 1><<<dim3((T + 127) / 128, 8), blk, 0, stream>>>(
        attn, Wo, Wo, Wo, bo, bo, bo, d_out, T, 1024, 1024);
  } else {
    ws_too_small_sentinel<<<1, 64, 0, stream>>>((float*)d_out);
  }
}